// Round 8
// baseline (475.065 us; speedup 1.0000x reference)
//
#include <hip/hip_runtime.h>
#include <hip/hip_bf16.h>

#define D_ 768
#define W_ 128
#define T_ 64
#define S_ 256
#define H_ 12
#define HH_ 6
#define BT_ 512

__device__ __forceinline__ unsigned short f2bf(float f) {
  unsigned u = __float_as_uint(f);
  u = (u + 0x7FFFu + ((u >> 16) & 1u)) >> 16;
  return (unsigned short)u;
}
__device__ __forceinline__ float bfu(unsigned s) {           // low 16 bits -> float
  return __uint_as_float(s << 16);
}

// K0: pack x -> packed[bt][sc][dd][s&15] (bf16) + pooled q[bt][d] (fp32).
__global__ __launch_bounds__(384) void k_pack(const float* __restrict__ x,
                                              unsigned short* __restrict__ packed,
                                              float* __restrict__ q) {
  const int blk  = blockIdx.x;
  const int cc   = blk & 15;
  const int tjp  = (blk >> 4) & 3;
  const int ti   = (blk >> 6) & 7;
  const int b    = blk >> 9;
  const int tid  = threadIdx.x;
  const int c8   = tid & 7;
  const int ch   = tid >> 3;
  const int btl  = c8 >> 2;
  const int btg0 = b*64 + ti*8 + tjp*2;
  const int ch0  = cc * 48;

  __shared__ unsigned short tile[48][2][260];
  __shared__ float poolsc[48][2];

  const float* xcol = x + (size_t)b*D_*16384 + (size_t)(ch0 + ch)*16384
                        + (16*ti)*128 + 32*tjp + c8*4;

  float psum = 0.f;
  #pragma unroll
  for (int r = 0; r < 16; ++r) {
    const float4 v = *(const float4*)(xcol + r*128);
    const int px = r*16 + (c8 & 3)*4;
    unsigned lo = (unsigned)f2bf(v.x) | ((unsigned)f2bf(v.y) << 16);
    unsigned hi = (unsigned)f2bf(v.z) | ((unsigned)f2bf(v.w) << 16);
    *(uint2*)&tile[ch][btl][px] = make_uint2(lo, hi);
    psum += (v.x + v.y) + (v.z + v.w);
  }
  psum += __shfl_xor(psum, 1);
  psum += __shfl_xor(psum, 2);
  if ((c8 & 3) == 0) poolsc[ch][btl] = psum;
  __syncthreads();

  for (int ii = tid; ii < 512; ii += 384) {
    const int bl = ii >> 8, p = ii & 255;
    unsigned short* pbt = packed + ((size_t)(btg0 + bl)*16 + cc)*D_*16;
    #pragma unroll
    for (int c = 0; c < 3; ++c) {
      unsigned u[8];
      #pragma unroll
      for (int k2 = 0; k2 < 8; ++k2) {
        const unsigned a  = tile[3*(2*k2)     + c][bl][p];
        const unsigned b2 = tile[3*(2*k2 + 1) + c][bl][p];
        u[k2] = a | (b2 << 16);
      }
      unsigned short* dst = pbt + (size_t)(c*256 + p)*16;
      *(uint4*)(dst)     = make_uint4(u[0], u[1], u[2], u[3]);
      *(uint4*)(dst + 8) = make_uint4(u[4], u[5], u[6], u[7]);
    }
  }
  if (tid < 96) {
    const int ch2 = tid >> 1, bl = tid & 1;
    q[(size_t)(btg0 + bl)*D_ + ch0 + ch2] = poolsc[ch2][bl] * (1.0f/256.0f);
  }
}

// K1: merged qp+fold per (bt-chunk of 16, head h):
//   qp[16][64] = q[16][:] . Wq[h*64+i][:] + bq  (LDS only)
//   qk[bt][h][dd] = bf16(0.125 * sum_i qp[bt][i] * Wk[h*64+i][dd])
__global__ __launch_bounds__(256) void k_qkf(const float* __restrict__ q,
                                             const float* __restrict__ ipw,
                                             const float* __restrict__ ipb,
                                             unsigned short* __restrict__ qkout) {
  const int h   = blockIdx.x >> 5;
  const int btc = blockIdx.x & 31;
  const int bt0 = btc * 16;
  const int tid = threadIdx.x;
  const int i = tid & 63, qw = tid >> 6;
  __shared__ float wt[64][65];    // 16.6 KB weight tile
  __shared__ float at[16][65];    // 4.2 KB activation tile
  __shared__ float qps[16][72];   // 4.6 KB qp result

  // ---- Phase A: qp rows h*64..h*64+63 (proven k_qp tile pattern) ----
  {
    const float* Wr = ipw + (size_t)h*64*D_;
    float acc[4] = {0,0,0,0};
    for (int dc = 0; dc < D_; dc += 64) {
      #pragma unroll
      for (int k = 0; k < 4; ++k) {
        const int idx = k*256 + tid;
        const int r = idx >> 4, c4 = idx & 15;
        *(float4*)&wt[r][c4*4] = *(const float4*)(Wr + (size_t)r*D_ + dc + c4*4);
      }
      {
        const int r = tid >> 4, c4 = tid & 15;
        *(float4*)&at[r][c4*4] = *(const float4*)(q + (size_t)(bt0 + r)*D_ + dc + c4*4);
      }
      __syncthreads();
      #pragma unroll
      for (int dd = 0; dd < 64; ++dd) {
        const float wv = wt[i][dd];
        #pragma unroll
        for (int k = 0; k < 4; ++k)
          acc[k] += at[qw + k*4][dd] * wv;
      }
      __syncthreads();
    }
    const float bqv = ipb[h*64 + i];
    #pragma unroll
    for (int k = 0; k < 4; ++k)
      qps[qw + k*4][i] = acc[k] + bqv;
  }
  __syncthreads();

  // ---- Phase B: fold with Wk rows h*64..+63, 64-dd tiles ----
  for (int ddc = 0; ddc < D_; ddc += 64) {
    #pragma unroll
    for (int k = 0; k < 4; ++k) {
      const int idx = k*256 + tid;
      const int r = idx >> 4, c4 = idx & 15;
      *(float4*)&wt[r][c4*4] = *(const float4*)(ipw + (size_t)(D_ + h*64 + r)*D_ + ddc + c4*4);
    }
    __syncthreads();
    float acc2[4] = {0,0,0,0};
    #pragma unroll 8
    for (int kk = 0; kk < 64; ++kk) {
      const float w = wt[kk][i];
      #pragma unroll
      for (int k = 0; k < 4; ++k)
        acc2[k] += qps[qw + k*4][kk] * w;
    }
    #pragma unroll
    for (int k = 0; k < 4; ++k)
      qkout[((size_t)(bt0 + qw + k*4)*H_ + h)*D_ + ddc + i] = f2bf(acc2[k] * 0.125f);
    __syncthreads();
  }
}

// K3: per (bt, head-half): scores -> softmax -> wsum -> ctx proj (fused).
// grid 1024: hg = blockIdx>>9, bt = blockIdx&511.
__global__ __launch_bounds__(256) void k_attn3(const unsigned short* __restrict__ packed,
                                               const unsigned short* __restrict__ qkin,
                                               const float* __restrict__ ipw,
                                               const float* __restrict__ ipb,
                                               float* __restrict__ ctx) {
  const int hg = blockIdx.x >> 9;
  const int bt = blockIdx.x & 511;
  const int tid = threadIdx.x;
  const int wv = tid >> 6, lane = tid & 63;
  __shared__ float pool_lds[HH_ * D_];   // 18 KB: qk -> reduce scratch -> w_lds
  __shared__ float sc[HH_][S_];          // 6 KB

  { // load qk (bf16) for this head-half -> f32 LDS
    const uint4* src = (const uint4*)(qkin + ((size_t)bt*H_ + hg*HH_)*D_);
    #pragma unroll
    for (int k = 0; k < 3; ++k) {
      const int idx = k*256 + tid;
      if (idx < 576) {
        const uint4 v = src[idx];
        float* d = pool_lds + idx*8;
        d[0] = bfu(v.x & 0xFFFFu); d[1] = bfu(v.x >> 16);
        d[2] = bfu(v.y & 0xFFFFu); d[3] = bfu(v.y >> 16);
        d[4] = bfu(v.z & 0xFFFFu); d[5] = bfu(v.z >> 16);
        d[6] = bfu(v.w & 0xFFFFu); d[7] = bfu(v.w >> 16);
      }
    }
  }
  __syncthreads();

  // ---- scores partials: wave owns d-quarter, lane owns (sc-chunk, s-offset) ----
  float acc[HH_][4];
  #pragma unroll
  for (int h = 0; h < HH_; ++h)
    #pragma unroll
    for (int j = 0; j < 4; ++j) acc[h][j] = 0.f;

  {
    const unsigned short* pb = packed + ((size_t)bt*16 + (lane >> 2))*D_*16 + (lane & 3)*4;
    const int d0 = wv * 192;
    #pragma unroll 4
    for (int d4 = 0; d4 < 48; ++d4) {
      const int d = d0 + d4*4;
      float f[4][4];
      #pragma unroll
      for (int dd = 0; dd < 4; ++dd) {
        const short4 pv = *(const short4*)(pb + (size_t)(d + dd)*16);
        f[dd][0] = bfu((unsigned)(unsigned short)pv.x);
        f[dd][1] = bfu((unsigned)(unsigned short)pv.y);
        f[dd][2] = bfu((unsigned)(unsigned short)pv.z);
        f[dd][3] = bfu((unsigned)(unsigned short)pv.w);
      }
      #pragma unroll
      for (int h = 0; h < HH_; ++h) {
        const float4 qv = *(const float4*)&pool_lds[h*D_ + d];
        #pragma unroll
        for (int j = 0; j < 4; ++j)
          acc[h][j] += qv.x*f[0][j] + qv.y*f[1][j] + qv.z*f[2][j] + qv.w*f[3][j];
      }
    }
  }
  __syncthreads();   // all waves done reading qk

  if (wv == 0) {
    #pragma unroll
    for (int h = 0; h < HH_; ++h)
      *(float4*)&sc[h][lane*4] = make_float4(acc[h][0], acc[h][1], acc[h][2], acc[h][3]);
  } else {
    float* dstp = pool_lds + (size_t)(wv - 1)*(HH_*S_);
    #pragma unroll
    for (int h = 0; h < HH_; ++h)
      *(float4*)&dstp[h*S_ + lane*4] = make_float4(acc[h][0], acc[h][1], acc[h][2], acc[h][3]);
  }
  __syncthreads();
  #pragma unroll
  for (int h = 0; h < HH_; ++h)
    sc[h][tid] += pool_lds[0*(HH_*S_) + h*S_ + tid]
                + pool_lds[1*(HH_*S_) + h*S_ + tid]
                + pool_lds[2*(HH_*S_) + h*S_ + tid];
  __syncthreads();

  // ---- softmax over s: waves 0-2, 2 heads each ----
  if (wv < 3) {
    #pragma unroll
    for (int hh = 0; hh < 2; ++hh) {
      const int h = wv*2 + hh;
      float4 v = *(const float4*)(&sc[h][lane*4]);
      float m = fmaxf(fmaxf(v.x, v.y), fmaxf(v.z, v.w));
      #pragma unroll
      for (int off = 32; off > 0; off >>= 1) m = fmaxf(m, __shfl_xor(m, off));
      const float e0 = __expf(v.x - m), e1 = __expf(v.y - m),
                  e2 = __expf(v.z - m), e3 = __expf(v.w - m);
      float ss = (e0+e1)+(e2+e3);
      #pragma unroll
      for (int off = 32; off > 0; off >>= 1) ss += __shfl_xor(ss, off);
      const float inv = 1.0f / ss;
      *(float4*)(&sc[h][lane*4]) = make_float4(e0*inv, e1*inv, e2*inv, e3*inv);
    }
  }
  __syncthreads();

  // ---- wsum: thread owns dd = c*256+tid ----
  float wacc[HH_][3];
  #pragma unroll
  for (int h = 0; h < HH_; ++h) { wacc[h][0]=0.f; wacc[h][1]=0.f; wacc[h][2]=0.f; }
  const unsigned short* prow = packed + (size_t)bt*16*D_*16;
  #pragma unroll 2
  for (int s8 = 0; s8 < 32; ++s8) {
    float f[3][8];
    #pragma unroll
    for (int c = 0; c < 3; ++c) {
      const uint4 pv = *(const uint4*)(prow + ((size_t)(s8 >> 1)*D_ + c*256 + tid)*16
                                            + (s8 & 1)*8);
      f[c][0] = bfu(pv.x & 0xFFFFu); f[c][1] = bfu(pv.x >> 16);
      f[c][2] = bfu(pv.y & 0xFFFFu); f[c][3] = bfu(pv.y >> 16);
      f[c][4] = bfu(pv.z & 0xFFFFu); f[c][5] = bfu(pv.z >> 16);
      f[c][6] = bfu(pv.w & 0xFFFFu); f[c][7] = bfu(pv.w >> 16);
    }
    #pragma unroll
    for (int h = 0; h < HH_; ++h) {
      const float4 a0 = *(const float4*)&sc[h][s8*8];
      const float4 a1 = *(const float4*)&sc[h][s8*8 + 4];
      #pragma unroll
      for (int c = 0; c < 3; ++c)
        wacc[h][c] += a0.x*f[c][0] + a0.y*f[c][1] + a0.z*f[c][2] + a0.w*f[c][3]
                    + a1.x*f[c][4] + a1.y*f[c][5] + a1.z*f[c][6] + a1.w*f[c][7];
    }
  }

  // ---- ctx proj (fused k_ctx): w -> LDS, lane dots its Wv row ----
  __syncthreads();              // pool_lds scratch reads long done
  float* w_lds = pool_lds;      // [6][768]
  #pragma unroll
  for (int h = 0; h < HH_; ++h)
    #pragma unroll
    for (int c = 0; c < 3; ++c)
      w_lds[h*D_ + c*256 + tid] = wacc[h][c];
  __syncthreads();

  for (int o = tid; o < HH_*64; o += 256) {
    const int hh = o >> 6, i = o & 63;
    const int hglob = hg*HH_ + hh;
    const float* wr = ipw + (size_t)(2*D_ + hglob*64 + i)*D_;
    const float* wl = w_lds + hh*D_;
    float a = 0.f;
    #pragma unroll 4
    for (int d4 = 0; d4 < 192; ++d4) {
      const float4 wv4 = *(const float4*)(wr + d4*4);
      const float4 ww  = *(const float4*)(wl + d4*4);
      a += wv4.x*ww.x + wv4.y*ww.y + wv4.z*ww.z + wv4.w*ww.w;
    }
    ctx[(size_t)bt*D_ + hglob*64 + i] = a + ipb[2*D_ + hglob*64 + i];
  }
}

// K4: out[bt][j] = ctx[bt][:] . ow[j][:] + ob[j]
__global__ __launch_bounds__(256) void k_out(const float* __restrict__ ctx,
                                             const float* __restrict__ ow,
                                             const float* __restrict__ ob,
                                             float* __restrict__ out) {
  const int jt = blockIdx.x >> 5;
  const int bt0 = (blockIdx.x & 31) * 16;
  const int tid = threadIdx.x;
  const float* Wr = ow + (size_t)jt*64*D_;
  __shared__ float wt[64][65];
  __shared__ float at[16][65];
  const int i = tid & 63, qw = tid >> 6;
  float acc[4] = {0,0,0,0};
  for (int dc = 0; dc < D_; dc += 64) {
    #pragma unroll
    for (int k = 0; k < 4; ++k) {
      const int idx = k*256 + tid;
      const int r = idx >> 4, c4 = idx & 15;
      *(float4*)&wt[r][c4*4] = *(const float4*)(Wr + (size_t)r*D_ + dc + c4*4);
    }
    {
      const int r = tid >> 4, c4 = tid & 15;
      *(float4*)&at[r][c4*4] = *(const float4*)(ctx + (size_t)(bt0 + r)*D_ + dc + c4*4);
    }
    __syncthreads();
    #pragma unroll
    for (int dd = 0; dd < 64; ++dd) {
      const float wv = wt[i][dd];
      #pragma unroll
      for (int k = 0; k < 4; ++k)
        acc[k] += at[qw + k*4][dd] * wv;
    }
    __syncthreads();
  }
  const float obv = ob[jt*64 + i];
  #pragma unroll
  for (int k = 0; k < 4; ++k)
    out[(size_t)(bt0 + qw + k*4)*D_ + jt*64 + i] = acc[k] + obv;
}

// ---------------- fallback path (small workspace) ----------------
__global__ __launch_bounds__(256) void k_q(const float* __restrict__ x, float* __restrict__ q) {
  const int bd = blockIdx.x;
  const int tid = threadIdx.x;
  const float4* xp = (const float4*)(x + (size_t)bd * (W_*W_));
  float acc[8] = {0,0,0,0,0,0,0,0};
  #pragma unroll
  for (int k = 0; k < 16; ++k) {
    float4 v = xp[k*256 + tid];
    acc[k>>1] += (v.x + v.y) + (v.z + v.w);
  }
  __shared__ float part[256][9];
  #pragma unroll
  for (int i = 0; i < 8; ++i) part[tid][i] = acc[i];
  __syncthreads();
  if (tid < 64) {
    const int ti = tid >> 3, tj = tid & 7;
    float s = 0.f;
    #pragma unroll
    for (int m = 0; m < 8; ++m)
      #pragma unroll
      for (int n = 0; n < 4; ++n)
        s += part[m*32 + tj*4 + n][ti];
    const int b = bd / D_, d = bd - b*D_;
    q[(size_t)(b*T_ + tid)*D_ + d] = s * (1.0f/256.0f);
  }
}

__global__ __launch_bounds__(256) void k_attn(const float* __restrict__ x,
                                              const unsigned short* __restrict__ qkin,
                                              float* __restrict__ wout) {
  const int bt = blockIdx.x;
  const int b = bt >> 6, t = bt & 63;
  const int ti = t >> 3, tj = t & 7;
  const int tid = threadIdx.x;
  __shared__ float qkl[H_*D_];
  __shared__ float sc[H_][S_];
  const float* xb = x + (size_t)b*D_*W_*W_ + ti*16*W_ + tj*16;
  {
    const uint4* src = (const uint4*)(qkin + (size_t)bt*H_*D_);
    #pragma unroll
    for (int k = 0; k < 5; ++k) {
      const int idx = k*256 + tid;
      if (idx < 1152) {
        const uint4 v = src[idx];
        float* d = qkl + idx*8;
        d[0] = bfu(v.x & 0xFFFFu); d[1] = bfu(v.x >> 16);
        d[2] = bfu(v.y & 0xFFFFu); d[3] = bfu(v.y >> 16);
        d[4] = bfu(v.z & 0xFFFFu); d[5] = bfu(v.z >> 16);
        d[6] = bfu(v.w & 0xFFFFu); d[7] = bfu(v.w >> 16);
      }
    }
  }
  __syncthreads();
  float acc[H_];
  #pragma unroll
  for (int h = 0; h < H_; ++h) acc[h] = 0.f;
  #pragma unroll
  for (int c = 0; c < 3; ++c) {
    const float* chp = xb + (size_t)(3*tid + c)*(W_*W_);
    for (int blk = 0; blk < 8; ++blk) {
      float4 v[8];
      #pragma unroll
      for (int u = 0; u < 8; ++u) {
        const int pg = blk*8 + u;
        v[u] = *(const float4*)(chp + (pg>>2)*W_ + (pg&3)*4);
      }
      const int dbase = c*256 + blk*32;
      #pragma unroll
      for (int h = 0; h < H_; ++h) {
        const float4* qh = (const float4*)(qkl + h*D_ + dbase);
        float s0 = 0.f;
        #pragma unroll
        for (int u = 0; u < 8; ++u) {
          const float4 qq = qh[u];
          s0 += qq.x*v[u].x + qq.y*v[u].y + qq.z*v[u].z + qq.w*v[u].w;
        }
        acc[h] += s0;
      }
    }
  }
  #pragma unroll
  for (int h = 0; h < H_; ++h) sc[h][tid] = acc[h];
  __syncthreads();
  {
    const int wv = tid >> 6, lane = tid & 63;
    #pragma unroll
    for (int hh = 0; hh < 3; ++hh) {
      const int h = wv*3 + hh;
      float4 v = *(const float4*)(&sc[h][lane*4]);
      float m = fmaxf(fmaxf(v.x, v.y), fmaxf(v.z, v.w));
      #pragma unroll
      for (int off = 32; off > 0; off >>= 1) m = fmaxf(m, __shfl_xor(m, off));
      const float e0 = __expf(v.x - m), e1 = __expf(v.y - m),
                  e2 = __expf(v.z - m), e3 = __expf(v.w - m);
      float ss = (e0+e1)+(e2+e3);
      #pragma unroll
      for (int off = 32; off > 0; off >>= 1) ss += __shfl_xor(ss, off);
      const float inv = 1.0f / ss;
      *(float4*)(&sc[h][lane*4]) = make_float4(e0*inv, e1*inv, e2*inv, e3*inv);
    }
  }
  __syncthreads();
  float wacc[H_][3];
  #pragma unroll
  for (int h = 0; h < H_; ++h) { wacc[h][0]=0.f; wacc[h][1]=0.f; wacc[h][2]=0.f; }
  const float* xp0 = xb + (tid>>4)*W_ + (tid&15);
  for (int s = 0; s < S_; ++s) {
    const float p0 = xp0[(size_t)(3*s+0)*(W_*W_)];
    const float p1 = xp0[(size_t)(3*s+1)*(W_*W_)];
    const float p2 = xp0[(size_t)(3*s+2)*(W_*W_)];
    #pragma unroll
    for (int h = 0; h < H_; ++h) {
      const float at = sc[h][s];
      wacc[h][0] += at*p0; wacc[h][1] += at*p1; wacc[h][2] += at*p2;
    }
  }
  float* wp = wout + (size_t)bt*H_*D_;
  #pragma unroll
  for (int h = 0; h < H_; ++h)
    #pragma unroll
    for (int c = 0; c < 3; ++c)
      wp[h*D_ + c*256 + tid] = wacc[h][c];
}

__global__ __launch_bounds__(256) void k_ctx(const float* __restrict__ wbuf,
                                             const float* __restrict__ ipw,
                                             const float* __restrict__ ipb,
                                             float* __restrict__ ctx) {
  const int h = blockIdx.x >> 5;
  const int bt0 = (blockIdx.x & 31) * 16;
  const int tid = threadIdx.x;
  const float* Wv = ipw + (size_t)2*D_*D_ + (size_t)h*64*D_;
  __shared__ float wt[64][65];
  __shared__ float at[16][65];
  const int i = tid & 63, qw = tid >> 6;
  float acc[4] = {0,0,0,0};
  for (int dc = 0; dc < D_; dc += 64) {
    #pragma unroll
    for (int k = 0; k < 4; ++k) {
      const int idx = k*256 + tid;
      const int r = idx >> 4, c4 = idx & 15;
      *(float4*)&wt[r][c4*4] = *(const float4*)(Wv + (size_t)r*D_ + dc + c4*4);
    }
    {
      const int r = tid >> 4, c4 = tid & 15;
      *(float4*)&at[r][c4*4] = *(const float4*)(wbuf + ((size_t)(bt0 + r)*H_ + h)*D_ + dc + c4*4);
    }
    __syncthreads();
    #pragma unroll
    for (int dd = 0; dd < 64; ++dd) {
      const float wv = wt[i][dd];
      #pragma unroll
      for (int k = 0; k < 4; ++k)
        acc[k] += at[qw + k*4][dd] * wv;
    }
    __syncthreads();
  }
  const float bvv = ipb[2*D_ + h*64 + i];
  #pragma unroll
  for (int k = 0; k < 4; ++k)
    ctx[(size_t)(bt0 + qw + k*4)*D_ + h*64 + i] = acc[k] + bvv;
}
// ------------------------------------------------------------------

extern "C" void kernel_launch(void* const* d_in, const int* in_sizes, int n_in,
                              void* d_out, int out_size, void* d_ws, size_t ws_size,
                              hipStream_t stream) {
  const float* x   = (const float*)d_in[0];
  const float* ipw = (const float*)d_in[1];
  const float* ipb = (const float*)d_in[2];
  const float* ow  = (const float*)d_in[3];
  const float* ob  = (const float*)d_in[4];
  float* out = (float*)d_out;

  float* q    = (float*)d_ws;                       // 1.5 MB
  float* qp   = q    + (size_t)BT_*D_;              // 1.5 MB (fallback only)
  unsigned short* qk = (unsigned short*)(qp + (size_t)BT_*D_);   // 9.4 MB bf16 (region 18.9)
  float* wb   = qp   + (size_t)BT_*D_ + (size_t)BT_*H_*D_;       // 18.9 MB (fallback only)
  float* ctxb = wb   + (size_t)BT_*H_*D_;           // 1.5 MB
  unsigned short* packed = (unsigned short*)(ctxb + (size_t)BT_*D_);  // 201.3 MB

  const size_t need_main = ((size_t)BT_*D_*3 + (size_t)BT_*H_*D_*2) * 4
                         + (size_t)BT_*D_*S_*2;

  if (ws_size >= need_main) {
    k_pack <<<dim3(4096), dim3(384), 0, stream>>>(x, packed, q);
    k_qkf  <<<dim3(384),  dim3(256), 0, stream>>>(q, ipw, ipb, qk);
    k_attn3<<<dim3(1024), dim3(256), 0, stream>>>(packed, qk, ipw, ipb, ctxb);
    k_out  <<<dim3(384),  dim3(256), 0, stream>>>(ctxb, ow, ob, out);
  } else {
    k_q    <<<dim3(8*D_), dim3(256), 0, stream>>>(x, q);
    k_qkf  <<<dim3(384),  dim3(256), 0, stream>>>(q, ipw, ipb, qk);
    k_attn <<<dim3(BT_),  dim3(256), 0, stream>>>(x, qk, wb);
    k_ctx  <<<dim3(384),  dim3(256), 0, stream>>>(wb, ipw, ipb, ctxb);
    k_out  <<<dim3(384),  dim3(256), 0, stream>>>(ctxb, ow, ob, out);
  }
}

// Round 9
// 422.949 us; speedup vs baseline: 1.1232x; 1.1232x over previous
//
#include <hip/hip_runtime.h>
#include <hip/hip_bf16.h>

#define D_ 768
#define W_ 128
#define T_ 64
#define S_ 256
#define H_ 12
#define HH_ 6
#define BT_ 512

__device__ __forceinline__ unsigned short f2bf(float f) {
  unsigned u = __float_as_uint(f);
  u = (u + 0x7FFFu + ((u >> 16) & 1u)) >> 16;
  return (unsigned short)u;
}
__device__ __forceinline__ float bfu(unsigned s) {           // low 16 bits -> float
  return __uint_as_float(s << 16);
}

// K0: pack x -> packed[bt][sc][dd][s&15] (bf16) + pooled q[bt][d] (fp32).
__global__ __launch_bounds__(384) void k_pack(const float* __restrict__ x,
                                              unsigned short* __restrict__ packed,
                                              float* __restrict__ q) {
  const int blk  = blockIdx.x;
  const int cc   = blk & 15;
  const int tjp  = (blk >> 4) & 3;
  const int ti   = (blk >> 6) & 7;
  const int b    = blk >> 9;
  const int tid  = threadIdx.x;
  const int c8   = tid & 7;
  const int ch   = tid >> 3;
  const int btl  = c8 >> 2;
  const int btg0 = b*64 + ti*8 + tjp*2;
  const int ch0  = cc * 48;

  __shared__ unsigned short tile[48][2][260];
  __shared__ float poolsc[48][2];

  const float* xcol = x + (size_t)b*D_*16384 + (size_t)(ch0 + ch)*16384
                        + (16*ti)*128 + 32*tjp + c8*4;

  float psum = 0.f;
  #pragma unroll
  for (int r = 0; r < 16; ++r) {
    const float4 v = *(const float4*)(xcol + r*128);
    const int px = r*16 + (c8 & 3)*4;
    unsigned lo = (unsigned)f2bf(v.x) | ((unsigned)f2bf(v.y) << 16);
    unsigned hi = (unsigned)f2bf(v.z) | ((unsigned)f2bf(v.w) << 16);
    *(uint2*)&tile[ch][btl][px] = make_uint2(lo, hi);
    psum += (v.x + v.y) + (v.z + v.w);
  }
  psum += __shfl_xor(psum, 1);
  psum += __shfl_xor(psum, 2);
  if ((c8 & 3) == 0) poolsc[ch][btl] = psum;
  __syncthreads();

  for (int ii = tid; ii < 512; ii += 384) {
    const int bl = ii >> 8, p = ii & 255;
    unsigned short* pbt = packed + ((size_t)(btg0 + bl)*16 + cc)*D_*16;
    #pragma unroll
    for (int c = 0; c < 3; ++c) {
      unsigned u[8];
      #pragma unroll
      for (int k2 = 0; k2 < 8; ++k2) {
        const unsigned a  = tile[3*(2*k2)     + c][bl][p];
        const unsigned b2 = tile[3*(2*k2 + 1) + c][bl][p];
        u[k2] = a | (b2 << 16);
      }
      unsigned short* dst = pbt + (size_t)(c*256 + p)*16;
      *(uint4*)(dst)     = make_uint4(u[0], u[1], u[2], u[3]);
      *(uint4*)(dst + 8) = make_uint4(u[4], u[5], u[6], u[7]);
    }
  }
  if (tid < 96) {
    const int ch2 = tid >> 1, bl = tid & 1;
    q[(size_t)(btg0 + bl)*D_ + ch0 + ch2] = poolsc[ch2][bl] * (1.0f/256.0f);
  }
}

// K1: merged qp+fold per (bt-chunk of 16, head h)
__global__ __launch_bounds__(256) void k_qkf(const float* __restrict__ q,
                                             const float* __restrict__ ipw,
                                             const float* __restrict__ ipb,
                                             unsigned short* __restrict__ qkout) {
  const int h   = blockIdx.x >> 5;
  const int btc = blockIdx.x & 31;
  const int bt0 = btc * 16;
  const int tid = threadIdx.x;
  const int i = tid & 63, qw = tid >> 6;
  __shared__ float wt[64][65];
  __shared__ float at[16][65];
  __shared__ float qps[16][72];

  {
    const float* Wr = ipw + (size_t)h*64*D_;
    float acc[4] = {0,0,0,0};
    for (int dc = 0; dc < D_; dc += 64) {
      #pragma unroll
      for (int k = 0; k < 4; ++k) {
        const int idx = k*256 + tid;
        const int r = idx >> 4, c4 = idx & 15;
        *(float4*)&wt[r][c4*4] = *(const float4*)(Wr + (size_t)r*D_ + dc + c4*4);
      }
      {
        const int r = tid >> 4, c4 = tid & 15;
        *(float4*)&at[r][c4*4] = *(const float4*)(q + (size_t)(bt0 + r)*D_ + dc + c4*4);
      }
      __syncthreads();
      #pragma unroll
      for (int dd = 0; dd < 64; ++dd) {
        const float wv = wt[i][dd];
        #pragma unroll
        for (int k = 0; k < 4; ++k)
          acc[k] += at[qw + k*4][dd] * wv;
      }
      __syncthreads();
    }
    const float bqv = ipb[h*64 + i];
    #pragma unroll
    for (int k = 0; k < 4; ++k)
      qps[qw + k*4][i] = acc[k] + bqv;
  }
  __syncthreads();

  for (int ddc = 0; ddc < D_; ddc += 64) {
    #pragma unroll
    for (int k = 0; k < 4; ++k) {
      const int idx = k*256 + tid;
      const int r = idx >> 4, c4 = idx & 15;
      *(float4*)&wt[r][c4*4] = *(const float4*)(ipw + (size_t)(D_ + h*64 + r)*D_ + ddc + c4*4);
    }
    __syncthreads();
    float acc2[4] = {0,0,0,0};
    #pragma unroll 8
    for (int kk = 0; kk < 64; ++kk) {
      const float w = wt[kk][i];
      #pragma unroll
      for (int k = 0; k < 4; ++k)
        acc2[k] += qps[qw + k*4][kk] * w;
    }
    #pragma unroll
    for (int k = 0; k < 4; ++k)
      qkout[((size_t)(bt0 + qw + k*4)*H_ + h)*D_ + ddc + i] = f2bf(acc2[k] * 0.125f);
    __syncthreads();
  }
}

// K3: per (bt, head-half): scores -> softmax -> wsum.
// grid 1024, hg-MINOR mapping: bt = blk>>1, hg = blk&1 (twins dispatch-adjacent
// -> second packed pass L2/L3-hot). Register prefetch in both stream loops.
__global__ __launch_bounds__(256) void k_attn3(const unsigned short* __restrict__ packed,
                                               const unsigned short* __restrict__ qkin,
                                               float* __restrict__ wout) {
  const int bt = blockIdx.x >> 1;
  const int hg = blockIdx.x & 1;
  const int tid = threadIdx.x;
  const int wv = tid >> 6, lane = tid & 63;
  __shared__ float pool_lds[HH_ * D_];   // 18 KB: qk -> reduce scratch
  __shared__ float sc[HH_][S_];          // 6 KB

  { // load qk (bf16) for this head-half -> f32 LDS
    const uint4* src = (const uint4*)(qkin + ((size_t)bt*H_ + hg*HH_)*D_);
    #pragma unroll
    for (int k = 0; k < 3; ++k) {
      const int idx = k*256 + tid;
      if (idx < 576) {
        const uint4 v = src[idx];
        float* d = pool_lds + idx*8;
        d[0] = bfu(v.x & 0xFFFFu); d[1] = bfu(v.x >> 16);
        d[2] = bfu(v.y & 0xFFFFu); d[3] = bfu(v.y >> 16);
        d[4] = bfu(v.z & 0xFFFFu); d[5] = bfu(v.z >> 16);
        d[6] = bfu(v.w & 0xFFFFu); d[7] = bfu(v.w >> 16);
      }
    }
  }
  __syncthreads();

  // ---- scores partials with register prefetch ----
  float acc[HH_][4];
  #pragma unroll
  for (int h = 0; h < HH_; ++h)
    #pragma unroll
    for (int j = 0; j < 4; ++j) acc[h][j] = 0.f;

  {
    const unsigned short* pb = packed + ((size_t)bt*16 + (lane >> 2))*D_*16 + (lane & 3)*4;
    const int d0 = wv * 192;
    short4 pv[4];
    #pragma unroll
    for (int dd = 0; dd < 4; ++dd)
      pv[dd] = *(const short4*)(pb + (size_t)(d0 + dd)*16);
    #pragma unroll 2
    for (int d4 = 0; d4 < 48; ++d4) {
      const int d = d0 + d4*4;
      short4 nx[4];
      if (d4 < 47) {
        #pragma unroll
        for (int dd = 0; dd < 4; ++dd)
          nx[dd] = *(const short4*)(pb + (size_t)(d + 4 + dd)*16);
      }
      float f[4][4];
      #pragma unroll
      for (int dd = 0; dd < 4; ++dd) {
        f[dd][0] = bfu((unsigned)(unsigned short)pv[dd].x);
        f[dd][1] = bfu((unsigned)(unsigned short)pv[dd].y);
        f[dd][2] = bfu((unsigned)(unsigned short)pv[dd].z);
        f[dd][3] = bfu((unsigned)(unsigned short)pv[dd].w);
      }
      #pragma unroll
      for (int h = 0; h < HH_; ++h) {
        const float4 qv = *(const float4*)&pool_lds[h*D_ + d];
        #pragma unroll
        for (int j = 0; j < 4; ++j)
          acc[h][j] += qv.x*f[0][j] + qv.y*f[1][j] + qv.z*f[2][j] + qv.w*f[3][j];
      }
      #pragma unroll
      for (int dd = 0; dd < 4; ++dd) pv[dd] = nx[dd];
    }
  }
  __syncthreads();   // all waves done reading qk

  if (wv == 0) {
    #pragma unroll
    for (int h = 0; h < HH_; ++h)
      *(float4*)&sc[h][lane*4] = make_float4(acc[h][0], acc[h][1], acc[h][2], acc[h][3]);
  } else {
    float* dstp = pool_lds + (size_t)(wv - 1)*(HH_*S_);
    #pragma unroll
    for (int h = 0; h < HH_; ++h)
      *(float4*)&dstp[h*S_ + lane*4] = make_float4(acc[h][0], acc[h][1], acc[h][2], acc[h][3]);
  }
  __syncthreads();
  #pragma unroll
  for (int h = 0; h < HH_; ++h)
    sc[h][tid] += pool_lds[0*(HH_*S_) + h*S_ + tid]
                + pool_lds[1*(HH_*S_) + h*S_ + tid]
                + pool_lds[2*(HH_*S_) + h*S_ + tid];
  __syncthreads();

  // ---- softmax over s: waves 0-2, 2 heads each ----
  if (wv < 3) {
    #pragma unroll
    for (int hh = 0; hh < 2; ++hh) {
      const int h = wv*2 + hh;
      float4 v = *(const float4*)(&sc[h][lane*4]);
      float m = fmaxf(fmaxf(v.x, v.y), fmaxf(v.z, v.w));
      #pragma unroll
      for (int off = 32; off > 0; off >>= 1) m = fmaxf(m, __shfl_xor(m, off));
      const float e0 = __expf(v.x - m), e1 = __expf(v.y - m),
                  e2 = __expf(v.z - m), e3 = __expf(v.w - m);
      float ss = (e0+e1)+(e2+e3);
      #pragma unroll
      for (int off = 32; off > 0; off >>= 1) ss += __shfl_xor(ss, off);
      const float inv = 1.0f / ss;
      *(float4*)(&sc[h][lane*4]) = make_float4(e0*inv, e1*inv, e2*inv, e3*inv);
    }
  }
  __syncthreads();

  // ---- wsum with register prefetch: thread owns dd = c*256+tid ----
  float wacc[HH_][3];
  #pragma unroll
  for (int h = 0; h < HH_; ++h) { wacc[h][0]=0.f; wacc[h][1]=0.f; wacc[h][2]=0.f; }
  const unsigned short* prow = packed + (size_t)bt*16*D_*16;
  uint4 pv3[3];
  #pragma unroll
  for (int c = 0; c < 3; ++c)
    pv3[c] = *(const uint4*)(prow + ((size_t)0*D_ + c*256 + tid)*16);
  #pragma unroll 2
  for (int s8 = 0; s8 < 32; ++s8) {
    uint4 nx3[3];
    if (s8 < 31) {
      const int t = s8 + 1;
      #pragma unroll
      for (int c = 0; c < 3; ++c)
        nx3[c] = *(const uint4*)(prow + ((size_t)(t >> 1)*D_ + c*256 + tid)*16 + (t & 1)*8);
    }
    float f[3][8];
    #pragma unroll
    for (int c = 0; c < 3; ++c) {
      f[c][0] = bfu(pv3[c].x & 0xFFFFu); f[c][1] = bfu(pv3[c].x >> 16);
      f[c][2] = bfu(pv3[c].y & 0xFFFFu); f[c][3] = bfu(pv3[c].y >> 16);
      f[c][4] = bfu(pv3[c].z & 0xFFFFu); f[c][5] = bfu(pv3[c].z >> 16);
      f[c][6] = bfu(pv3[c].w & 0xFFFFu); f[c][7] = bfu(pv3[c].w >> 16);
    }
    #pragma unroll
    for (int h = 0; h < HH_; ++h) {
      const float4 a0 = *(const float4*)&sc[h][s8*8];
      const float4 a1 = *(const float4*)&sc[h][s8*8 + 4];
      #pragma unroll
      for (int c = 0; c < 3; ++c)
        wacc[h][c] += a0.x*f[c][0] + a0.y*f[c][1] + a0.z*f[c][2] + a0.w*f[c][3]
                    + a1.x*f[c][4] + a1.y*f[c][5] + a1.z*f[c][6] + a1.w*f[c][7];
    }
    #pragma unroll
    for (int c = 0; c < 3; ++c) pv3[c] = nx3[c];
  }
  float* wp = wout + ((size_t)bt*H_ + hg*HH_)*D_;
  #pragma unroll
  for (int h = 0; h < HH_; ++h)
    #pragma unroll
    for (int c = 0; c < 3; ++c)
      wp[h*D_ + c*256 + tid] = wacc[h][c];
}

// K4a: ctx[bt][h*64+i] = sum_d w[bt][h][d] * Wv[h*64+i][d] + bv   (768 blocks)
__global__ __launch_bounds__(256) void k_ctx(const float* __restrict__ wbuf,
                                             const float* __restrict__ ipw,
                                             const float* __restrict__ ipb,
                                             float* __restrict__ ctx) {
  const int h = blockIdx.x >> 6;
  const int bt0 = (blockIdx.x & 63) * 8;
  const int tid = threadIdx.x;
  const float* Wv = ipw + (size_t)2*D_*D_ + (size_t)h*64*D_;
  __shared__ float wt[64][65];
  __shared__ float at[8][65];
  const int i = tid & 63, qw = tid >> 6;
  float acc[2] = {0,0};
  for (int dc = 0; dc < D_; dc += 64) {
    #pragma unroll
    for (int k = 0; k < 4; ++k) {
      const int idx = k*256 + tid;
      const int r = idx >> 4, c4 = idx & 15;
      *(float4*)&wt[r][c4*4] = *(const float4*)(Wv + (size_t)r*D_ + dc + c4*4);
    }
    if (tid < 128) {
      const int r = tid >> 4, c4 = tid & 15;
      *(float4*)&at[r][c4*4] = *(const float4*)(wbuf + ((size_t)(bt0 + r)*H_ + h)*D_ + dc + c4*4);
    }
    __syncthreads();
    #pragma unroll
    for (int dd = 0; dd < 64; ++dd) {
      const float wv = wt[i][dd];
      #pragma unroll
      for (int k = 0; k < 2; ++k)
        acc[k] += at[qw + k*4][dd] * wv;
    }
    __syncthreads();
  }
  const float bvv = ipb[2*D_ + h*64 + i];
  #pragma unroll
  for (int k = 0; k < 2; ++k)
    ctx[(size_t)(bt0 + qw + k*4)*D_ + h*64 + i] = acc[k] + bvv;
}

// K4b: out[bt][j] = ctx[bt][:] . ow[j][:] + ob[j]   (768 blocks)
__global__ __launch_bounds__(256) void k_out(const float* __restrict__ ctx,
                                             const float* __restrict__ ow,
                                             const float* __restrict__ ob,
                                             float* __restrict__ out) {
  const int jt = blockIdx.x >> 6;
  const int bt0 = (blockIdx.x & 63) * 8;
  const int tid = threadIdx.x;
  const float* Wr = ow + (size_t)jt*64*D_;
  __shared__ float wt[64][65];
  __shared__ float at[8][65];
  const int i = tid & 63, qw = tid >> 6;
  float acc[2] = {0,0};
  for (int dc = 0; dc < D_; dc += 64) {
    #pragma unroll
    for (int k = 0; k < 4; ++k) {
      const int idx = k*256 + tid;
      const int r = idx >> 4, c4 = idx & 15;
      *(float4*)&wt[r][c4*4] = *(const float4*)(Wr + (size_t)r*D_ + dc + c4*4);
    }
    if (tid < 128) {
      const int r = tid >> 4, c4 = tid & 15;
      *(float4*)&at[r][c4*4] = *(const float4*)(ctx + (size_t)(bt0 + r)*D_ + dc + c4*4);
    }
    __syncthreads();
    #pragma unroll
    for (int dd = 0; dd < 64; ++dd) {
      const float wv = wt[i][dd];
      #pragma unroll
      for (int k = 0; k < 2; ++k)
        acc[k] += at[qw + k*4][dd] * wv;
    }
    __syncthreads();
  }
  const float obv = ob[jt*64 + i];
  #pragma unroll
  for (int k = 0; k < 2; ++k)
    out[(size_t)(bt0 + qw + k*4)*D_ + jt*64 + i] = acc[k] + obv;
}

// ---------------- fallback path (small workspace) ----------------
__global__ __launch_bounds__(256) void k_q(const float* __restrict__ x, float* __restrict__ q) {
  const int bd = blockIdx.x;
  const int tid = threadIdx.x;
  const float4* xp = (const float4*)(x + (size_t)bd * (W_*W_));
  float acc[8] = {0,0,0,0,0,0,0,0};
  #pragma unroll
  for (int k = 0; k < 16; ++k) {
    float4 v = xp[k*256 + tid];
    acc[k>>1] += (v.x + v.y) + (v.z + v.w);
  }
  __shared__ float part[256][9];
  #pragma unroll
  for (int i = 0; i < 8; ++i) part[tid][i] = acc[i];
  __syncthreads();
  if (tid < 64) {
    const int ti = tid >> 3, tj = tid & 7;
    float s = 0.f;
    #pragma unroll
    for (int m = 0; m < 8; ++m)
      #pragma unroll
      for (int n = 0; n < 4; ++n)
        s += part[m*32 + tj*4 + n][ti];
    const int b = bd / D_, d = bd - b*D_;
    q[(size_t)(b*T_ + tid)*D_ + d] = s * (1.0f/256.0f);
  }
}

__global__ __launch_bounds__(256) void k_attn(const float* __restrict__ x,
                                              const unsigned short* __restrict__ qkin,
                                              float* __restrict__ wout) {
  const int bt = blockIdx.x;
  const int b = bt >> 6, t = bt & 63;
  const int ti = t >> 3, tj = t & 7;
  const int tid = threadIdx.x;
  __shared__ float qkl[H_*D_];
  __shared__ float sc[H_][S_];
  const float* xb = x + (size_t)b*D_*W_*W_ + ti*16*W_ + tj*16;
  {
    const uint4* src = (const uint4*)(qkin + (size_t)bt*H_*D_);
    #pragma unroll
    for (int k = 0; k < 5; ++k) {
      const int idx = k*256 + tid;
      if (idx < 1152) {
        const uint4 v = src[idx];
        float* d = qkl + idx*8;
        d[0] = bfu(v.x & 0xFFFFu); d[1] = bfu(v.x >> 16);
        d[2] = bfu(v.y & 0xFFFFu); d[3] = bfu(v.y >> 16);
        d[4] = bfu(v.z & 0xFFFFu); d[5] = bfu(v.z >> 16);
        d[6] = bfu(v.w & 0xFFFFu); d[7] = bfu(v.w >> 16);
      }
    }
  }
  __syncthreads();
  float acc[H_];
  #pragma unroll
  for (int h = 0; h < H_; ++h) acc[h] = 0.f;
  #pragma unroll
  for (int c = 0; c < 3; ++c) {
    const float* chp = xb + (size_t)(3*tid + c)*(W_*W_);
    for (int blk = 0; blk < 8; ++blk) {
      float4 v[8];
      #pragma unroll
      for (int u = 0; u < 8; ++u) {
        const int pg = blk*8 + u;
        v[u] = *(const float4*)(chp + (pg>>2)*W_ + (pg&3)*4);
      }
      const int dbase = c*256 + blk*32;
      #pragma unroll
      for (int h = 0; h < H_; ++h) {
        const float4* qh = (const float4*)(qkl + h*D_ + dbase);
        float s0 = 0.f;
        #pragma unroll
        for (int u = 0; u < 8; ++u) {
          const float4 qq = qh[u];
          s0 += qq.x*v[u].x + qq.y*v[u].y + qq.z*v[u].z + qq.w*v[u].w;
        }
        acc[h] += s0;
      }
    }
  }
  #pragma unroll
  for (int h = 0; h < H_; ++h) sc[h][tid] = acc[h];
  __syncthreads();
  {
    const int wv = tid >> 6, lane = tid & 63;
    #pragma unroll
    for (int hh = 0; hh < 3; ++hh) {
      const int h = wv*3 + hh;
      float4 v = *(const float4*)(&sc[h][lane*4]);
      float m = fmaxf(fmaxf(v.x, v.y), fmaxf(v.z, v.w));
      #pragma unroll
      for (int off = 32; off > 0; off >>= 1) m = fmaxf(m, __shfl_xor(m, off));
      const float e0 = __expf(v.x - m), e1 = __expf(v.y - m),
                  e2 = __expf(v.z - m), e3 = __expf(v.w - m);
      float ss = (e0+e1)+(e2+e3);
      #pragma unroll
      for (int off = 32; off > 0; off >>= 1) ss += __shfl_xor(ss, off);
      const float inv = 1.0f / ss;
      *(float4*)(&sc[h][lane*4]) = make_float4(e0*inv, e1*inv, e2*inv, e3*inv);
    }
  }
  __syncthreads();
  float wacc[H_][3];
  #pragma unroll
  for (int h = 0; h < H_; ++h) { wacc[h][0]=0.f; wacc[h][1]=0.f; wacc[h][2]=0.f; }
  const float* xp0 = xb + (tid>>4)*W_ + (tid&15);
  for (int s = 0; s < S_; ++s) {
    const float p0 = xp0[(size_t)(3*s+0)*(W_*W_)];
    const float p1 = xp0[(size_t)(3*s+1)*(W_*W_)];
    const float p2 = xp0[(size_t)(3*s+2)*(W_*W_)];
    #pragma unroll
    for (int h = 0; h < H_; ++h) {
      const float at = sc[h][s];
      wacc[h][0] += at*p0; wacc[h][1] += at*p1; wacc[h][2] += at*p2;
    }
  }
  float* wp = wout + (size_t)bt*H_*D_;
  #pragma unroll
  for (int h = 0; h < H_; ++h)
    #pragma unroll
    for (int c = 0; c < 3; ++c)
      wp[h*D_ + c*256 + tid] = wacc[h][c];
}
// ------------------------------------------------------------------

extern "C" void kernel_launch(void* const* d_in, const int* in_sizes, int n_in,
                              void* d_out, int out_size, void* d_ws, size_t ws_size,
                              hipStream_t stream) {
  const float* x   = (const float*)d_in[0];
  const float* ipw = (const float*)d_in[1];
  const float* ipb = (const float*)d_in[2];
  const float* ow  = (const float*)d_in[3];
  const float* ob  = (const float*)d_in[4];
  float* out = (float*)d_out;

  float* q    = (float*)d_ws;                       // 1.5 MB
  float* qp   = q    + (size_t)BT_*D_;              // 1.5 MB (fallback only)
  unsigned short* qk = (unsigned short*)(qp + (size_t)BT_*D_);   // bf16 (region 18.9 MB)
  float* wb   = qp   + (size_t)BT_*D_ + (size_t)BT_*H_*D_;       // 18.9 MB
  float* ctxb = wb   + (size_t)BT_*H_*D_;           // 1.5 MB
  unsigned short* packed = (unsigned short*)(ctxb + (size_t)BT_*D_);  // 201.3 MB

  const size_t need_main = ((size_t)BT_*D_*3 + (size_t)BT_*H_*D_*2) * 4
                         + (size_t)BT_*D_*S_*2;

  if (ws_size >= need_main) {
    k_pack <<<dim3(4096), dim3(384), 0, stream>>>(x, packed, q);
    k_qkf  <<<dim3(384),  dim3(256), 0, stream>>>(q, ipw, ipb, qk);
    k_attn3<<<dim3(1024), dim3(256), 0, stream>>>(packed, qk, wb);
    k_ctx  <<<dim3(768),  dim3(256), 0, stream>>>(wb, ipw, ipb, ctxb);
    k_out  <<<dim3(768),  dim3(256), 0, stream>>>(ctxb, ow, ob, out);
  } else {
    k_q    <<<dim3(8*D_), dim3(256), 0, stream>>>(x, q);
    k_qkf  <<<dim3(384),  dim3(256), 0, stream>>>(q, ipw, ipb, qk);
    k_attn <<<dim3(BT_),  dim3(256), 0, stream>>>(x, qk, wb);
    k_ctx  <<<dim3(768),  dim3(256), 0, stream>>>(wb, ipw, ipb, ctxb);
    k_out  <<<dim3(768),  dim3(256), 0, stream>>>(ctxb, ow, ob, out);
  }
}

// Round 10
// 383.321 us; speedup vs baseline: 1.2393x; 1.1034x over previous
//
#include <hip/hip_runtime.h>
#include <hip/hip_bf16.h>

#define D_ 768
#define W_ 128
#define T_ 64
#define S_ 256
#define H_ 12
#define HH_ 6
#define BT_ 512

__device__ __forceinline__ unsigned short f2bf(float f) {
  unsigned u = __float_as_uint(f);
  u = (u + 0x7FFFu + ((u >> 16) & 1u)) >> 16;
  return (unsigned short)u;
}
__device__ __forceinline__ float bfu(unsigned s) {           // low 16 bits -> float
  return __uint_as_float(s << 16);
}

// K0: pack x -> packed[bt][sc][dd][s&15] (bf16) + pooled q[bt][d] (fp32).
__global__ __launch_bounds__(384) void k_pack(const float* __restrict__ x,
                                              unsigned short* __restrict__ packed,
                                              float* __restrict__ q) {
  const int blk  = blockIdx.x;
  const int cc   = blk & 15;
  const int tjp  = (blk >> 4) & 3;
  const int ti   = (blk >> 6) & 7;
  const int b    = blk >> 9;
  const int tid  = threadIdx.x;
  const int c8   = tid & 7;
  const int ch   = tid >> 3;
  const int btl  = c8 >> 2;
  const int btg0 = b*64 + ti*8 + tjp*2;
  const int ch0  = cc * 48;

  __shared__ unsigned short tile[48][2][260];
  __shared__ float poolsc[48][2];

  const float* xcol = x + (size_t)b*D_*16384 + (size_t)(ch0 + ch)*16384
                        + (16*ti)*128 + 32*tjp + c8*4;

  float psum = 0.f;
  #pragma unroll
  for (int r = 0; r < 16; ++r) {
    const float4 v = *(const float4*)(xcol + r*128);
    const int px = r*16 + (c8 & 3)*4;
    unsigned lo = (unsigned)f2bf(v.x) | ((unsigned)f2bf(v.y) << 16);
    unsigned hi = (unsigned)f2bf(v.z) | ((unsigned)f2bf(v.w) << 16);
    *(uint2*)&tile[ch][btl][px] = make_uint2(lo, hi);
    psum += (v.x + v.y) + (v.z + v.w);
  }
  psum += __shfl_xor(psum, 1);
  psum += __shfl_xor(psum, 2);
  if ((c8 & 3) == 0) poolsc[ch][btl] = psum;
  __syncthreads();

  for (int ii = tid; ii < 512; ii += 384) {
    const int bl = ii >> 8, p = ii & 255;
    unsigned short* pbt = packed + ((size_t)(btg0 + bl)*16 + cc)*D_*16;
    #pragma unroll
    for (int c = 0; c < 3; ++c) {
      unsigned u[8];
      #pragma unroll
      for (int k2 = 0; k2 < 8; ++k2) {
        const unsigned a  = tile[3*(2*k2)     + c][bl][p];
        const unsigned b2 = tile[3*(2*k2 + 1) + c][bl][p];
        u[k2] = a | (b2 << 16);
      }
      unsigned short* dst = pbt + (size_t)(c*256 + p)*16;
      *(uint4*)(dst)     = make_uint4(u[0], u[1], u[2], u[3]);
      *(uint4*)(dst + 8) = make_uint4(u[4], u[5], u[6], u[7]);
    }
  }
  if (tid < 96) {
    const int ch2 = tid >> 1, bl = tid & 1;
    q[(size_t)(btg0 + bl)*D_ + ch0 + ch2] = poolsc[ch2][bl] * (1.0f/256.0f);
  }
}

// K2a: qp[bt][j] = q[bt][:] . Wq[j][:] + bq[j]   (768 blocks, bt-chunk 8)
__global__ __launch_bounds__(256) void k_qp(const float* __restrict__ q,
                                            const float* __restrict__ ipw,
                                            const float* __restrict__ ipb,
                                            float* __restrict__ qp) {
  const int jt = blockIdx.x >> 6;
  const int bt0 = (blockIdx.x & 63) * 8;
  const int tid = threadIdx.x;
  const float* Wr = ipw + (size_t)jt*64*D_;
  __shared__ float wt[64][65];
  __shared__ float at[8][65];
  const int i = tid & 63, qw = tid >> 6;
  float acc[2] = {0,0};
  for (int dc = 0; dc < D_; dc += 64) {
    #pragma unroll
    for (int k = 0; k < 4; ++k) {
      const int idx = k*256 + tid;
      const int r = idx >> 4, c4 = idx & 15;
      *(float4*)&wt[r][c4*4] = *(const float4*)(Wr + (size_t)r*D_ + dc + c4*4);
    }
    if (tid < 128) {
      const int r = tid >> 4, c4 = tid & 15;
      *(float4*)&at[r][c4*4] = *(const float4*)(q + (size_t)(bt0 + r)*D_ + dc + c4*4);
    }
    __syncthreads();
    #pragma unroll
    for (int dd = 0; dd < 64; ++dd) {
      const float wv = wt[i][dd];
      #pragma unroll
      for (int k = 0; k < 2; ++k)
        acc[k] += at[qw + k*4][dd] * wv;
    }
    __syncthreads();
  }
  const float bqv = ipb[jt*64 + i];
  #pragma unroll
  for (int k = 0; k < 2; ++k)
    qp[(size_t)(bt0 + qw + k*4)*D_ + jt*64 + i] = acc[k] + bqv;
}

// K2b: qk[bt][h][dd] = bf16(0.125 * sum_i qp[bt][h*64+i] * Wk[h*64+i][dd])
__global__ __launch_bounds__(256) void k_fold(const float* __restrict__ qp,
                                              const float* __restrict__ ipw,
                                              unsigned short* __restrict__ qkout) {
  const int btc = blockIdx.x & 15;
  const int nt  = blockIdx.x >> 4;
  const int h   = nt / 12;
  const int ddc = (nt % 12) * 64;
  const int bt0 = btc * 32;
  const int tid = threadIdx.x;
  __shared__ float qpl[32][68];
  __shared__ float wkl[64][68];
  #pragma unroll
  for (int k = 0; k < 2; ++k) {
    const int idx = k*256 + tid;
    const int r = idx >> 4, c4 = idx & 15;
    *(float4*)&qpl[r][c4*4] = *(const float4*)(qp + (size_t)(bt0 + r)*D_ + h*64 + c4*4);
  }
  #pragma unroll
  for (int k = 0; k < 4; ++k) {
    const int idx = k*256 + tid;
    const int r = idx >> 4, c4 = idx & 15;
    *(float4*)&wkl[r][c4*4] = *(const float4*)(ipw + (size_t)(D_ + h*64 + r)*D_ + ddc + c4*4);
  }
  __syncthreads();
  const int i = tid & 63, qw = tid >> 6;
  float acc[8] = {0,0,0,0,0,0,0,0};
  #pragma unroll 8
  for (int kk = 0; kk < 64; ++kk) {
    const float w = wkl[kk][i];
    #pragma unroll
    for (int k = 0; k < 8; ++k)
      acc[k] += qpl[qw + k*4][kk] * w;
  }
  #pragma unroll
  for (int k = 0; k < 8; ++k)
    qkout[((size_t)(bt0 + qw + k*4)*H_ + h)*D_ + ddc + i] = f2bf(acc[k] * 0.125f);
}

// K3: per (bt, head-half): scores -> softmax -> wsum -> wb (bf16).
// hg-minor: bt = blk>>1, hg = blk&1. Register prefetch in both stream loops.
__global__ __launch_bounds__(256) void k_attn3(const unsigned short* __restrict__ packed,
                                               const unsigned short* __restrict__ qkin,
                                               unsigned short* __restrict__ wout) {
  const int bt = blockIdx.x >> 1;
  const int hg = blockIdx.x & 1;
  const int tid = threadIdx.x;
  const int wv = tid >> 6, lane = tid & 63;
  __shared__ float pool_lds[HH_ * D_];   // 18 KB: qk -> reduce scratch
  __shared__ float sc[HH_][S_];          // 6 KB

  { // load qk (bf16) for this head-half -> f32 LDS
    const uint4* src = (const uint4*)(qkin + ((size_t)bt*H_ + hg*HH_)*D_);
    #pragma unroll
    for (int k = 0; k < 3; ++k) {
      const int idx = k*256 + tid;
      if (idx < 576) {
        const uint4 v = src[idx];
        float* d = pool_lds + idx*8;
        d[0] = bfu(v.x & 0xFFFFu); d[1] = bfu(v.x >> 16);
        d[2] = bfu(v.y & 0xFFFFu); d[3] = bfu(v.y >> 16);
        d[4] = bfu(v.z & 0xFFFFu); d[5] = bfu(v.z >> 16);
        d[6] = bfu(v.w & 0xFFFFu); d[7] = bfu(v.w >> 16);
      }
    }
  }
  __syncthreads();

  // ---- scores partials with register prefetch ----
  float acc[HH_][4];
  #pragma unroll
  for (int h = 0; h < HH_; ++h)
    #pragma unroll
    for (int j = 0; j < 4; ++j) acc[h][j] = 0.f;

  {
    const unsigned short* pb = packed + ((size_t)bt*16 + (lane >> 2))*D_*16 + (lane & 3)*4;
    const int d0 = wv * 192;
    short4 pv[4];
    #pragma unroll
    for (int dd = 0; dd < 4; ++dd)
      pv[dd] = *(const short4*)(pb + (size_t)(d0 + dd)*16);
    #pragma unroll 2
    for (int d4 = 0; d4 < 48; ++d4) {
      const int d = d0 + d4*4;
      short4 nx[4];
      if (d4 < 47) {
        #pragma unroll
        for (int dd = 0; dd < 4; ++dd)
          nx[dd] = *(const short4*)(pb + (size_t)(d + 4 + dd)*16);
      }
      float f[4][4];
      #pragma unroll
      for (int dd = 0; dd < 4; ++dd) {
        f[dd][0] = bfu((unsigned)(unsigned short)pv[dd].x);
        f[dd][1] = bfu((unsigned)(unsigned short)pv[dd].y);
        f[dd][2] = bfu((unsigned)(unsigned short)pv[dd].z);
        f[dd][3] = bfu((unsigned)(unsigned short)pv[dd].w);
      }
      #pragma unroll
      for (int h = 0; h < HH_; ++h) {
        const float4 qv = *(const float4*)&pool_lds[h*D_ + d];
        #pragma unroll
        for (int j = 0; j < 4; ++j)
          acc[h][j] += qv.x*f[0][j] + qv.y*f[1][j] + qv.z*f[2][j] + qv.w*f[3][j];
      }
      #pragma unroll
      for (int dd = 0; dd < 4; ++dd) pv[dd] = nx[dd];
    }
  }
  __syncthreads();   // all waves done reading qk

  if (wv == 0) {
    #pragma unroll
    for (int h = 0; h < HH_; ++h)
      *(float4*)&sc[h][lane*4] = make_float4(acc[h][0], acc[h][1], acc[h][2], acc[h][3]);
  } else {
    float* dstp = pool_lds + (size_t)(wv - 1)*(HH_*S_);
    #pragma unroll
    for (int h = 0; h < HH_; ++h)
      *(float4*)&dstp[h*S_ + lane*4] = make_float4(acc[h][0], acc[h][1], acc[h][2], acc[h][3]);
  }
  __syncthreads();
  #pragma unroll
  for (int h = 0; h < HH_; ++h)
    sc[h][tid] += pool_lds[0*(HH_*S_) + h*S_ + tid]
                + pool_lds[1*(HH_*S_) + h*S_ + tid]
                + pool_lds[2*(HH_*S_) + h*S_ + tid];
  __syncthreads();

  // ---- softmax over s: waves 0-2, 2 heads each ----
  if (wv < 3) {
    #pragma unroll
    for (int hh = 0; hh < 2; ++hh) {
      const int h = wv*2 + hh;
      float4 v = *(const float4*)(&sc[h][lane*4]);
      float m = fmaxf(fmaxf(v.x, v.y), fmaxf(v.z, v.w));
      #pragma unroll
      for (int off = 32; off > 0; off >>= 1) m = fmaxf(m, __shfl_xor(m, off));
      const float e0 = __expf(v.x - m), e1 = __expf(v.y - m),
                  e2 = __expf(v.z - m), e3 = __expf(v.w - m);
      float ss = (e0+e1)+(e2+e3);
      #pragma unroll
      for (int off = 32; off > 0; off >>= 1) ss += __shfl_xor(ss, off);
      const float inv = 1.0f / ss;
      *(float4*)(&sc[h][lane*4]) = make_float4(e0*inv, e1*inv, e2*inv, e3*inv);
    }
  }
  __syncthreads();

  // ---- wsum with register prefetch: thread owns dd = c*256+tid ----
  float wacc[HH_][3];
  #pragma unroll
  for (int h = 0; h < HH_; ++h) { wacc[h][0]=0.f; wacc[h][1]=0.f; wacc[h][2]=0.f; }
  const unsigned short* prow = packed + (size_t)bt*16*D_*16;
  uint4 pv3[3];
  #pragma unroll
  for (int c = 0; c < 3; ++c)
    pv3[c] = *(const uint4*)(prow + ((size_t)0*D_ + c*256 + tid)*16);
  #pragma unroll 2
  for (int s8 = 0; s8 < 32; ++s8) {
    uint4 nx3[3];
    if (s8 < 31) {
      const int t = s8 + 1;
      #pragma unroll
      for (int c = 0; c < 3; ++c)
        nx3[c] = *(const uint4*)(prow + ((size_t)(t >> 1)*D_ + c*256 + tid)*16 + (t & 1)*8);
    }
    float f[3][8];
    #pragma unroll
    for (int c = 0; c < 3; ++c) {
      f[c][0] = bfu(pv3[c].x & 0xFFFFu); f[c][1] = bfu(pv3[c].x >> 16);
      f[c][2] = bfu(pv3[c].y & 0xFFFFu); f[c][3] = bfu(pv3[c].y >> 16);
      f[c][4] = bfu(pv3[c].z & 0xFFFFu); f[c][5] = bfu(pv3[c].z >> 16);
      f[c][6] = bfu(pv3[c].w & 0xFFFFu); f[c][7] = bfu(pv3[c].w >> 16);
    }
    #pragma unroll
    for (int h = 0; h < HH_; ++h) {
      const float4 a0 = *(const float4*)&sc[h][s8*8];
      const float4 a1 = *(const float4*)&sc[h][s8*8 + 4];
      #pragma unroll
      for (int c = 0; c < 3; ++c)
        wacc[h][c] += a0.x*f[c][0] + a0.y*f[c][1] + a0.z*f[c][2] + a0.w*f[c][3]
                    + a1.x*f[c][4] + a1.y*f[c][5] + a1.z*f[c][6] + a1.w*f[c][7];
    }
    #pragma unroll
    for (int c = 0; c < 3; ++c) pv3[c] = nx3[c];
  }
  unsigned short* wp = wout + ((size_t)bt*H_ + hg*HH_)*D_;
  #pragma unroll
  for (int h = 0; h < HH_; ++h)
    #pragma unroll
    for (int c = 0; c < 3; ++c)
      wp[h*D_ + c*256 + tid] = f2bf(wacc[h][c]);
}

// K4a: ctx[bt][h*64+i] = sum_d w[bt][h][d](bf16) * Wv[h*64+i][d] + bv  (768 blocks)
__global__ __launch_bounds__(256) void k_ctx(const unsigned short* __restrict__ wbuf,
                                             const float* __restrict__ ipw,
                                             const float* __restrict__ ipb,
                                             float* __restrict__ ctx) {
  const int h = blockIdx.x >> 6;
  const int bt0 = (blockIdx.x & 63) * 8;
  const int tid = threadIdx.x;
  const float* Wv = ipw + (size_t)2*D_*D_ + (size_t)h*64*D_;
  __shared__ float wt[64][65];
  __shared__ float at[8][65];
  const int i = tid & 63, qw = tid >> 6;
  float acc[2] = {0,0};
  for (int dc = 0; dc < D_; dc += 64) {
    #pragma unroll
    for (int k = 0; k < 4; ++k) {
      const int idx = k*256 + tid;
      const int r = idx >> 4, c4 = idx & 15;
      *(float4*)&wt[r][c4*4] = *(const float4*)(Wv + (size_t)r*D_ + dc + c4*4);
    }
    if (tid < 128) {
      const int r = tid >> 4, c4 = tid & 15;
      const uint2 v = *(const uint2*)(wbuf + ((size_t)(bt0 + r)*H_ + h)*D_ + dc + c4*4);
      at[r][c4*4 + 0] = bfu(v.x & 0xFFFFu);
      at[r][c4*4 + 1] = bfu(v.x >> 16);
      at[r][c4*4 + 2] = bfu(v.y & 0xFFFFu);
      at[r][c4*4 + 3] = bfu(v.y >> 16);
    }
    __syncthreads();
    #pragma unroll
    for (int dd = 0; dd < 64; ++dd) {
      const float wv = wt[i][dd];
      #pragma unroll
      for (int k = 0; k < 2; ++k)
        acc[k] += at[qw + k*4][dd] * wv;
    }
    __syncthreads();
  }
  const float bvv = ipb[2*D_ + h*64 + i];
  #pragma unroll
  for (int k = 0; k < 2; ++k)
    ctx[(size_t)(bt0 + qw + k*4)*D_ + h*64 + i] = acc[k] + bvv;
}

// K4b: out[bt][j] = ctx[bt][:] . ow[j][:] + ob[j]   (768 blocks)
__global__ __launch_bounds__(256) void k_out(const float* __restrict__ ctx,
                                             const float* __restrict__ ow,
                                             const float* __restrict__ ob,
                                             float* __restrict__ out) {
  const int jt = blockIdx.x >> 6;
  const int bt0 = (blockIdx.x & 63) * 8;
  const int tid = threadIdx.x;
  const float* Wr = ow + (size_t)jt*64*D_;
  __shared__ float wt[64][65];
  __shared__ float at[8][65];
  const int i = tid & 63, qw = tid >> 6;
  float acc[2] = {0,0};
  for (int dc = 0; dc < D_; dc += 64) {
    #pragma unroll
    for (int k = 0; k < 4; ++k) {
      const int idx = k*256 + tid;
      const int r = idx >> 4, c4 = idx & 15;
      *(float4*)&wt[r][c4*4] = *(const float4*)(Wr + (size_t)r*D_ + dc + c4*4);
    }
    if (tid < 128) {
      const int r = tid >> 4, c4 = tid & 15;
      *(float4*)&at[r][c4*4] = *(const float4*)(ctx + (size_t)(bt0 + r)*D_ + dc + c4*4);
    }
    __syncthreads();
    #pragma unroll
    for (int dd = 0; dd < 64; ++dd) {
      const float wv = wt[i][dd];
      #pragma unroll
      for (int k = 0; k < 2; ++k)
        acc[k] += at[qw + k*4][dd] * wv;
    }
    __syncthreads();
  }
  const float obv = ob[jt*64 + i];
  #pragma unroll
  for (int k = 0; k < 2; ++k)
    out[(size_t)(bt0 + qw + k*4)*D_ + jt*64 + i] = acc[k] + obv;
}

// ---------------- fallback path (small workspace) ----------------
__global__ __launch_bounds__(256) void k_q(const float* __restrict__ x, float* __restrict__ q) {
  const int bd = blockIdx.x;
  const int tid = threadIdx.x;
  const float4* xp = (const float4*)(x + (size_t)bd * (W_*W_));
  float acc[8] = {0,0,0,0,0,0,0,0};
  #pragma unroll
  for (int k = 0; k < 16; ++k) {
    float4 v = xp[k*256 + tid];
    acc[k>>1] += (v.x + v.y) + (v.z + v.w);
  }
  __shared__ float part[256][9];
  #pragma unroll
  for (int i = 0; i < 8; ++i) part[tid][i] = acc[i];
  __syncthreads();
  if (tid < 64) {
    const int ti = tid >> 3, tj = tid & 7;
    float s = 0.f;
    #pragma unroll
    for (int m = 0; m < 8; ++m)
      #pragma unroll
      for (int n = 0; n < 4; ++n)
        s += part[m*32 + tj*4 + n][ti];
    const int b = bd / D_, d = bd - b*D_;
    q[(size_t)(b*T_ + tid)*D_ + d] = s * (1.0f/256.0f);
  }
}

__global__ __launch_bounds__(256) void k_attn(const float* __restrict__ x,
                                              const unsigned short* __restrict__ qkin,
                                              unsigned short* __restrict__ wout) {
  const int bt = blockIdx.x;
  const int b = bt >> 6, t = bt & 63;
  const int ti = t >> 3, tj = t & 7;
  const int tid = threadIdx.x;
  __shared__ float qkl[H_*D_];
  __shared__ float sc[H_][S_];
  const float* xb = x + (size_t)b*D_*W_*W_ + ti*16*W_ + tj*16;
  {
    const uint4* src = (const uint4*)(qkin + (size_t)bt*H_*D_);
    #pragma unroll
    for (int k = 0; k < 5; ++k) {
      const int idx = k*256 + tid;
      if (idx < 1152) {
        const uint4 v = src[idx];
        float* d = qkl + idx*8;
        d[0] = bfu(v.x & 0xFFFFu); d[1] = bfu(v.x >> 16);
        d[2] = bfu(v.y & 0xFFFFu); d[3] = bfu(v.y >> 16);
        d[4] = bfu(v.z & 0xFFFFu); d[5] = bfu(v.z >> 16);
        d[6] = bfu(v.w & 0xFFFFu); d[7] = bfu(v.w >> 16);
      }
    }
  }
  __syncthreads();
  float acc[H_];
  #pragma unroll
  for (int h = 0; h < H_; ++h) acc[h] = 0.f;
  #pragma unroll
  for (int c = 0; c < 3; ++c) {
    const float* chp = xb + (size_t)(3*tid + c)*(W_*W_);
    for (int blk = 0; blk < 8; ++blk) {
      float4 v[8];
      #pragma unroll
      for (int u = 0; u < 8; ++u) {
        const int pg = blk*8 + u;
        v[u] = *(const float4*)(chp + (pg>>2)*W_ + (pg&3)*4);
      }
      const int dbase = c*256 + blk*32;
      #pragma unroll
      for (int h = 0; h < H_; ++h) {
        const float4* qh = (const float4*)(qkl + h*D_ + dbase);
        float s0 = 0.f;
        #pragma unroll
        for (int u = 0; u < 8; ++u) {
          const float4 qq = qh[u];
          s0 += qq.x*v[u].x + qq.y*v[u].y + qq.z*v[u].z + qq.w*v[u].w;
        }
        acc[h] += s0;
      }
    }
  }
  #pragma unroll
  for (int h = 0; h < H_; ++h) sc[h][tid] = acc[h];
  __syncthreads();
  {
    const int wv = tid >> 6, lane = tid & 63;
    #pragma unroll
    for (int hh = 0; hh < 3; ++hh) {
      const int h = wv*3 + hh;
      float4 v = *(const float4*)(&sc[h][lane*4]);
      float m = fmaxf(fmaxf(v.x, v.y), fmaxf(v.z, v.w));
      #pragma unroll
      for (int off = 32; off > 0; off >>= 1) m = fmaxf(m, __shfl_xor(m, off));
      const float e0 = __expf(v.x - m), e1 = __expf(v.y - m),
                  e2 = __expf(v.z - m), e3 = __expf(v.w - m);
      float ss = (e0+e1)+(e2+e3);
      #pragma unroll
      for (int off = 32; off > 0; off >>= 1) ss += __shfl_xor(ss, off);
      const float inv = 1.0f / ss;
      *(float4*)(&sc[h][lane*4]) = make_float4(e0*inv, e1*inv, e2*inv, e3*inv);
    }
  }
  __syncthreads();
  float wacc[H_][3];
  #pragma unroll
  for (int h = 0; h < H_; ++h) { wacc[h][0]=0.f; wacc[h][1]=0.f; wacc[h][2]=0.f; }
  const float* xp0 = xb + (tid>>4)*W_ + (tid&15);
  for (int s = 0; s < S_; ++s) {
    const float p0 = xp0[(size_t)(3*s+0)*(W_*W_)];
    const float p1 = xp0[(size_t)(3*s+1)*(W_*W_)];
    const float p2 = xp0[(size_t)(3*s+2)*(W_*W_)];
    #pragma unroll
    for (int h = 0; h < H_; ++h) {
      const float at = sc[h][s];
      wacc[h][0] += at*p0; wacc[h][1] += at*p1; wacc[h][2] += at*p2;
    }
  }
  unsigned short* wp = wout + (size_t)bt*H_*D_;
  #pragma unroll
  for (int h = 0; h < H_; ++h)
    #pragma unroll
    for (int c = 0; c < 3; ++c)
      wp[h*D_ + c*256 + tid] = f2bf(wacc[h][c]);
}
// ------------------------------------------------------------------

extern "C" void kernel_launch(void* const* d_in, const int* in_sizes, int n_in,
                              void* d_out, int out_size, void* d_ws, size_t ws_size,
                              hipStream_t stream) {
  const float* x   = (const float*)d_in[0];
  const float* ipw = (const float*)d_in[1];
  const float* ipb = (const float*)d_in[2];
  const float* ow  = (const float*)d_in[3];
  const float* ob  = (const float*)d_in[4];
  float* out = (float*)d_out;

  float* q    = (float*)d_ws;                       // 1.5 MB
  float* qp   = q    + (size_t)BT_*D_;              // 1.5 MB
  unsigned short* qk = (unsigned short*)(qp + (size_t)BT_*D_);   // bf16 (region 18.9 MB)
  unsigned short* wb = (unsigned short*)(qp + (size_t)BT_*D_ + (size_t)BT_*H_*D_);  // bf16 (region 18.9 MB)
  float* ctxb = qp + (size_t)BT_*D_ + (size_t)BT_*H_*D_*2;       // 1.5 MB
  unsigned short* packed = (unsigned short*)(ctxb + (size_t)BT_*D_);  // 201.3 MB

  const size_t need_main = ((size_t)BT_*D_*3 + (size_t)BT_*H_*D_*2) * 4
                         + (size_t)BT_*D_*S_*2;

  if (ws_size >= need_main) {
    k_pack <<<dim3(4096), dim3(384), 0, stream>>>(x, packed, q);
    k_qp   <<<dim3(768),  dim3(256), 0, stream>>>(q, ipw, ipb, qp);
    k_fold <<<dim3(2304), dim3(256), 0, stream>>>(qp, ipw, qk);
    k_attn3<<<dim3(1024), dim3(256), 0, stream>>>(packed, qk, wb);
    k_ctx  <<<dim3(768),  dim3(256), 0, stream>>>(wb, ipw, ipb, ctxb);
    k_out  <<<dim3(768),  dim3(256), 0, stream>>>(ctxb, ow, ob, out);
  } else {
    k_q    <<<dim3(8*D_), dim3(256), 0, stream>>>(x, q);
    k_qp   <<<dim3(768),  dim3(256), 0, stream>>>(q, ipw, ipb, qp);
    k_fold <<<dim3(2304), dim3(256), 0, stream>>>(qp, ipw, qk);
    k_attn <<<dim3(BT_),  dim3(256), 0, stream>>>(x, qk, wb);
    k_ctx  <<<dim3(768),  dim3(256), 0, stream>>>(wb, ipw, ipb, ctxb);
    k_out  <<<dim3(768),  dim3(256), 0, stream>>>(ctxb, ow, ob, out);
  }
}

// Round 11
// 342.843 us; speedup vs baseline: 1.3857x; 1.1181x over previous
//
#include <hip/hip_runtime.h>
#include <hip/hip_bf16.h>

#define D_ 768
#define W_ 128
#define T_ 64
#define S_ 256
#define H_ 12
#define BT_ 512

typedef __attribute__((ext_vector_type(8))) short short8v;
typedef __attribute__((ext_vector_type(4))) float f32x4;

__device__ __forceinline__ unsigned short f2bf(float f) {
  unsigned u = __float_as_uint(f);
  u = (u + 0x7FFFu + ((u >> 16) & 1u)) >> 16;
  return (unsigned short)u;
}
__device__ __forceinline__ float bfu(unsigned s) {           // low 16 bits -> float
  return __uint_as_float(s << 16);
}

// K0: pack x -> packed_s[bt][s][dd] (bf16, s-major) + pooled q[bt][d] (fp32).
//   s = ch/3 (channel triple), dd = (ch%3)*256 + pixel.  Row = 768 dd = 1536B.
__global__ __launch_bounds__(384) void k_pack(const float* __restrict__ x,
                                              unsigned short* __restrict__ packed,
                                              float* __restrict__ q) {
  const int blk  = blockIdx.x;
  const int cc   = blk & 15;
  const int tjp  = (blk >> 4) & 3;
  const int ti   = (blk >> 6) & 7;
  const int b    = blk >> 9;
  const int tid  = threadIdx.x;
  const int c8   = tid & 7;
  const int ch   = tid >> 3;
  const int btl  = c8 >> 2;
  const int btg0 = b*64 + ti*8 + tjp*2;
  const int ch0  = cc * 48;

  __shared__ unsigned short tile[48][2][264];   // 50.7 KB (264: 16B-aligned rows)
  __shared__ float poolsc[48][2];

  const float* xcol = x + (size_t)b*D_*16384 + (size_t)(ch0 + ch)*16384
                        + (16*ti)*128 + 32*tjp + c8*4;

  float psum = 0.f;
  #pragma unroll
  for (int r = 0; r < 16; ++r) {
    const float4 v = *(const float4*)(xcol + r*128);
    const int px = r*16 + (c8 & 3)*4;
    unsigned lo = (unsigned)f2bf(v.x) | ((unsigned)f2bf(v.y) << 16);
    unsigned hi = (unsigned)f2bf(v.z) | ((unsigned)f2bf(v.w) << 16);
    *(uint2*)&tile[ch][btl][px] = make_uint2(lo, hi);
    psum += (v.x + v.y) + (v.z + v.w);
  }
  psum += __shfl_xor(psum, 1);
  psum += __shfl_xor(psum, 2);
  if ((c8 & 3) == 0) poolsc[ch][btl] = psum;
  __syncthreads();

  // readout: 3072 uint4 units = 2 btl x 16 s x 3 c x 32 p8; contiguous dest
  for (int ii = tid; ii < 3072; ii += 384) {
    const int btl2 = ii / 1536;
    const int r2   = ii - btl2*1536;
    const int sl   = r2 / 96;
    const int r3   = r2 - sl*96;
    const int c    = r3 >> 5;
    const int p8   = r3 & 31;
    const int chs  = sl*3 + c;
    const uint4 v = *(const uint4*)&tile[chs][btl2][p8*8];
    unsigned short* dst = packed + (size_t)(btg0 + btl2)*(S_*D_)
                        + (size_t)(cc*16 + sl)*D_ + c*256 + p8*8;
    *(uint4*)dst = v;
  }
  if (tid < 96) {
    const int ch2 = tid >> 1, bl = tid & 1;
    q[(size_t)(btg0 + bl)*D_ + ch0 + ch2] = poolsc[ch2][bl] * (1.0f/256.0f);
  }
}

// K2a: qp[bt][j] = q[bt][:] . Wq[j][:] + bq[j]   (768 blocks, bt-chunk 8)
__global__ __launch_bounds__(256) void k_qp(const float* __restrict__ q,
                                            const float* __restrict__ ipw,
                                            const float* __restrict__ ipb,
                                            float* __restrict__ qp) {
  const int jt = blockIdx.x >> 6;
  const int bt0 = (blockIdx.x & 63) * 8;
  const int tid = threadIdx.x;
  const float* Wr = ipw + (size_t)jt*64*D_;
  __shared__ float wt[64][65];
  __shared__ float at[8][65];
  const int i = tid & 63, qw = tid >> 6;
  float acc[2] = {0,0};
  for (int dc = 0; dc < D_; dc += 64) {
    #pragma unroll
    for (int k = 0; k < 4; ++k) {
      const int idx = k*256 + tid;
      const int r = idx >> 4, c4 = idx & 15;
      *(float4*)&wt[r][c4*4] = *(const float4*)(Wr + (size_t)r*D_ + dc + c4*4);
    }
    if (tid < 128) {
      const int r = tid >> 4, c4 = tid & 15;
      *(float4*)&at[r][c4*4] = *(const float4*)(q + (size_t)(bt0 + r)*D_ + dc + c4*4);
    }
    __syncthreads();
    #pragma unroll
    for (int dd = 0; dd < 64; ++dd) {
      const float wv = wt[i][dd];
      #pragma unroll
      for (int k = 0; k < 2; ++k)
        acc[k] += at[qw + k*4][dd] * wv;
    }
    __syncthreads();
  }
  const float bqv = ipb[jt*64 + i];
  #pragma unroll
  for (int k = 0; k < 2; ++k)
    qp[(size_t)(bt0 + qw + k*4)*D_ + jt*64 + i] = acc[k] + bqv;
}

// K2b: qk[bt][h][dd] = bf16(0.125 * sum_i qp[bt][h*64+i] * Wk[h*64+i][dd])
__global__ __launch_bounds__(256) void k_fold(const float* __restrict__ qp,
                                              const float* __restrict__ ipw,
                                              unsigned short* __restrict__ qkout) {
  const int btc = blockIdx.x & 15;
  const int nt  = blockIdx.x >> 4;
  const int h   = nt / 12;
  const int ddc = (nt % 12) * 64;
  const int bt0 = btc * 32;
  const int tid = threadIdx.x;
  __shared__ float qpl[32][68];
  __shared__ float wkl[64][68];
  #pragma unroll
  for (int k = 0; k < 2; ++k) {
    const int idx = k*256 + tid;
    const int r = idx >> 4, c4 = idx & 15;
    *(float4*)&qpl[r][c4*4] = *(const float4*)(qp + (size_t)(bt0 + r)*D_ + h*64 + c4*4);
  }
  #pragma unroll
  for (int k = 0; k < 4; ++k) {
    const int idx = k*256 + tid;
    const int r = idx >> 4, c4 = idx & 15;
    *(float4*)&wkl[r][c4*4] = *(const float4*)(ipw + (size_t)(D_ + h*64 + r)*D_ + ddc + c4*4);
  }
  __syncthreads();
  const int i = tid & 63, qw = tid >> 6;
  float acc[8] = {0,0,0,0,0,0,0,0};
  #pragma unroll 8
  for (int kk = 0; kk < 64; ++kk) {
    const float w = wkl[kk][i];
    #pragma unroll
    for (int k = 0; k < 8; ++k)
      acc[k] += qpl[qw + k*4][kk] * w;
  }
  #pragma unroll
  for (int k = 0; k < 8; ++k)
    qkout[((size_t)(bt0 + qw + k*4)*H_ + h)*D_ + ddc + i] = f2bf(acc[k] * 0.125f);
}

// K3: per bt, 512 threads: MFMA scores -> softmax -> wsum -> wb (bf16).
// scores GEMM: C[s][h] = packed_s[256 s][768 d] x qk^T[768 d][12 h] via
// mfma_f32_16x16x32_bf16. A: lane m=l&15 (s), k=(l>>4)*8+j. B: lane n=l&15 (h).
// C (m89-verified): col=lane&15 (h), row=(lane>>4)*4+reg (s).
__global__ __launch_bounds__(512) void k_attn4(const unsigned short* __restrict__ packed,
                                               const unsigned short* __restrict__ qkin,
                                               unsigned short* __restrict__ wout) {
  const int bt = blockIdx.x;
  const int tid = threadIdx.x;
  const int wv = tid >> 6, lane = tid & 63;
  __shared__ float sc[12][260];    // 12.5 KB; scores then attn in-place

  const int m16 = lane & 15;
  const int kg  = lane >> 4;
  const unsigned short* pbase = packed + (size_t)bt * (S_*D_);

  { // ---- scores MFMA: wave wv covers s in [wv*32, wv*32+32) ----
    const int hB = (m16 < 12) ? m16 : 0;
    const unsigned short* qb  = qkin + ((size_t)bt*H_ + hB)*D_ + kg*8;
    const unsigned short* pA0 = pbase + (size_t)(wv*32      + m16)*D_ + kg*8;
    const unsigned short* pA1 = pbase + (size_t)(wv*32 + 16 + m16)*D_ + kg*8;
    f32x4 acc0 = {0.f,0.f,0.f,0.f};
    f32x4 acc1 = {0.f,0.f,0.f,0.f};
    #pragma unroll 4
    for (int ks = 0; ks < 24; ++ks) {
      const short8v b  = *(const short8v*)(qb  + ks*32);
      const short8v a0 = *(const short8v*)(pA0 + ks*32);
      const short8v a1 = *(const short8v*)(pA1 + ks*32);
      acc0 = __builtin_amdgcn_mfma_f32_16x16x32_bf16(a0, b, acc0, 0, 0, 0);
      acc1 = __builtin_amdgcn_mfma_f32_16x16x32_bf16(a1, b, acc1, 0, 0, 0);
    }
    if (m16 < 12) {
      #pragma unroll
      for (int r = 0; r < 4; ++r) {
        sc[m16][wv*32      + kg*4 + r] = acc0[r];
        sc[m16][wv*32 + 16 + kg*4 + r] = acc1[r];
      }
    }
  }
  __syncthreads();

  // ---- softmax over s: wave wv -> h = wv; waves 0-3 also h = 8+wv ----
  #pragma unroll
  for (int pass = 0; pass < 2; ++pass) {
    if (pass == 0 || wv < 4) {
      const int h = (pass == 0) ? wv : 8 + wv;
      float4 v = *(const float4*)(&sc[h][lane*4]);
      float m = fmaxf(fmaxf(v.x, v.y), fmaxf(v.z, v.w));
      #pragma unroll
      for (int off = 32; off > 0; off >>= 1) m = fmaxf(m, __shfl_xor(m, off));
      const float e0 = __expf(v.x - m), e1 = __expf(v.y - m),
                  e2 = __expf(v.z - m), e3 = __expf(v.w - m);
      float ss = (e0+e1)+(e2+e3);
      #pragma unroll
      for (int off = 32; off > 0; off >>= 1) ss += __shfl_xor(ss, off);
      const float inv = 1.0f / ss;
      *(float4*)(&sc[h][lane*4]) = make_float4(e0*inv, e1*inv, e2*inv, e3*inv);
    }
  }
  __syncthreads();

  // ---- wsum: 384 threads: hb = (tid/96)*3 (4 h-groups), dd8 = (tid%96)*8 ----
  if (tid < 384) {
    const int hb  = (tid / 96) * 3;
    const int dd8 = (tid - (hb/3)*96) * 8;   // (tid%96)*8
    float wacc[3][8];
    #pragma unroll
    for (int hh = 0; hh < 3; ++hh)
      #pragma unroll
      for (int j = 0; j < 8; ++j) wacc[hh][j] = 0.f;
    const unsigned short* pr = pbase + dd8;
    uint4 cur = *(const uint4*)pr;
    #pragma unroll 2
    for (int s = 0; s < 256; ++s) {
      uint4 nx = make_uint4(0,0,0,0);
      if (s < 255) nx = *(const uint4*)(pr + (size_t)(s + 1)*D_);
      float f[8];
      f[0] = bfu(cur.x & 0xFFFFu); f[1] = bfu(cur.x >> 16);
      f[2] = bfu(cur.y & 0xFFFFu); f[3] = bfu(cur.y >> 16);
      f[4] = bfu(cur.z & 0xFFFFu); f[5] = bfu(cur.z >> 16);
      f[6] = bfu(cur.w & 0xFFFFu); f[7] = bfu(cur.w >> 16);
      const float a0 = sc[hb + 0][s];
      const float a1 = sc[hb + 1][s];
      const float a2 = sc[hb + 2][s];
      #pragma unroll
      for (int j = 0; j < 8; ++j) {
        wacc[0][j] += a0 * f[j];
        wacc[1][j] += a1 * f[j];
        wacc[2][j] += a2 * f[j];
      }
      cur = nx;
    }
    unsigned short* wp = wout + ((size_t)bt*H_ + hb)*D_ + dd8;
    #pragma unroll
    for (int hh = 0; hh < 3; ++hh) {
      uint4 o;
      o.x = (unsigned)f2bf(wacc[hh][0]) | ((unsigned)f2bf(wacc[hh][1]) << 16);
      o.y = (unsigned)f2bf(wacc[hh][2]) | ((unsigned)f2bf(wacc[hh][3]) << 16);
      o.z = (unsigned)f2bf(wacc[hh][4]) | ((unsigned)f2bf(wacc[hh][5]) << 16);
      o.w = (unsigned)f2bf(wacc[hh][6]) | ((unsigned)f2bf(wacc[hh][7]) << 16);
      *(uint4*)(wp + (size_t)hh*D_) = o;
    }
  }
}

// K4a: ctx[bt][h*64+i] = sum_d w[bt][h][d](bf16) * Wv[h*64+i][d] + bv  (768 blocks)
__global__ __launch_bounds__(256) void k_ctx(const unsigned short* __restrict__ wbuf,
                                             const float* __restrict__ ipw,
                                             const float* __restrict__ ipb,
                                             float* __restrict__ ctx) {
  const int h = blockIdx.x >> 6;
  const int bt0 = (blockIdx.x & 63) * 8;
  const int tid = threadIdx.x;
  const float* Wv = ipw + (size_t)2*D_*D_ + (size_t)h*64*D_;
  __shared__ float wt[64][65];
  __shared__ float at[8][65];
  const int i = tid & 63, qw = tid >> 6;
  float acc[2] = {0,0};
  for (int dc = 0; dc < D_; dc += 64) {
    #pragma unroll
    for (int k = 0; k < 4; ++k) {
      const int idx = k*256 + tid;
      const int r = idx >> 4, c4 = idx & 15;
      *(float4*)&wt[r][c4*4] = *(const float4*)(Wv + (size_t)r*D_ + dc + c4*4);
    }
    if (tid < 128) {
      const int r = tid >> 4, c4 = tid & 15;
      const uint2 v = *(const uint2*)(wbuf + ((size_t)(bt0 + r)*H_ + h)*D_ + dc + c4*4);
      at[r][c4*4 + 0] = bfu(v.x & 0xFFFFu);
      at[r][c4*4 + 1] = bfu(v.x >> 16);
      at[r][c4*4 + 2] = bfu(v.y & 0xFFFFu);
      at[r][c4*4 + 3] = bfu(v.y >> 16);
    }
    __syncthreads();
    #pragma unroll
    for (int dd = 0; dd < 64; ++dd) {
      const float wv = wt[i][dd];
      #pragma unroll
      for (int k = 0; k < 2; ++k)
        acc[k] += at[qw + k*4][dd] * wv;
    }
    __syncthreads();
  }
  const float bvv = ipb[2*D_ + h*64 + i];
  #pragma unroll
  for (int k = 0; k < 2; ++k)
    ctx[(size_t)(bt0 + qw + k*4)*D_ + h*64 + i] = acc[k] + bvv;
}

// K4b: out[bt][j] = ctx[bt][:] . ow[j][:] + ob[j]   (768 blocks)
__global__ __launch_bounds__(256) void k_out(const float* __restrict__ ctx,
                                             const float* __restrict__ ow,
                                             const float* __restrict__ ob,
                                             float* __restrict__ out) {
  const int jt = blockIdx.x >> 6;
  const int bt0 = (blockIdx.x & 63) * 8;
  const int tid = threadIdx.x;
  const float* Wr = ow + (size_t)jt*64*D_;
  __shared__ float wt[64][65];
  __shared__ float at[8][65];
  const int i = tid & 63, qw = tid >> 6;
  float acc[2] = {0,0};
  for (int dc = 0; dc < D_; dc += 64) {
    #pragma unroll
    for (int k = 0; k < 4; ++k) {
      const int idx = k*256 + tid;
      const int r = idx >> 4, c4 = idx & 15;
      *(float4*)&wt[r][c4*4] = *(const float4*)(Wr + (size_t)r*D_ + dc + c4*4);
    }
    if (tid < 128) {
      const int r = tid >> 4, c4 = tid & 15;
      *(float4*)&at[r][c4*4] = *(const float4*)(ctx + (size_t)(bt0 + r)*D_ + dc + c4*4);
    }
    __syncthreads();
    #pragma unroll
    for (int dd = 0; dd < 64; ++dd) {
      const float wv = wt[i][dd];
      #pragma unroll
      for (int k = 0; k < 2; ++k)
        acc[k] += at[qw + k*4][dd] * wv;
    }
    __syncthreads();
  }
  const float obv = ob[jt*64 + i];
  #pragma unroll
  for (int k = 0; k < 2; ++k)
    out[(size_t)(bt0 + qw + k*4)*D_ + jt*64 + i] = acc[k] + obv;
}

// ---------------- fallback path (small workspace) ----------------
__global__ __launch_bounds__(256) void k_q(const float* __restrict__ x, float* __restrict__ q) {
  const int bd = blockIdx.x;
  const int tid = threadIdx.x;
  const float4* xp = (const float4*)(x + (size_t)bd * (W_*W_));
  float acc[8] = {0,0,0,0,0,0,0,0};
  #pragma unroll
  for (int k = 0; k < 16; ++k) {
    float4 v = xp[k*256 + tid];
    acc[k>>1] += (v.x + v.y) + (v.z + v.w);
  }
  __shared__ float part[256][9];
  #pragma unroll
  for (int i = 0; i < 8; ++i) part[tid][i] = acc[i];
  __syncthreads();
  if (tid < 64) {
    const int ti = tid >> 3, tj = tid & 7;
    float s = 0.f;
    #pragma unroll
    for (int m = 0; m < 8; ++m)
      #pragma unroll
      for (int n = 0; n < 4; ++n)
        s += part[m*32 + tj*4 + n][ti];
    const int b = bd / D_, d = bd - b*D_;
    q[(size_t)(b*T_ + tid)*D_ + d] = s * (1.0f/256.0f);
  }
}

__global__ __launch_bounds__(256) void k_attn(const float* __restrict__ x,
                                              const unsigned short* __restrict__ qkin,
                                              unsigned short* __restrict__ wout) {
  const int bt = blockIdx.x;
  const int b = bt >> 6, t = bt & 63;
  const int ti = t >> 3, tj = t & 7;
  const int tid = threadIdx.x;
  __shared__ float qkl[H_*D_];
  __shared__ float sc[H_][S_];
  const float* xb = x + (size_t)b*D_*W_*W_ + ti*16*W_ + tj*16;
  {
    const uint4* src = (const uint4*)(qkin + (size_t)bt*H_*D_);
    #pragma unroll
    for (int k = 0; k < 5; ++k) {
      const int idx = k*256 + tid;
      if (idx < 1152) {
        const uint4 v = src[idx];
        float* d = qkl + idx*8;
        d[0] = bfu(v.x & 0xFFFFu); d[1] = bfu(v.x >> 16);
        d[2] = bfu(v.y & 0xFFFFu); d[3] = bfu(v.y >> 16);
        d[4] = bfu(v.z & 0xFFFFu); d[5] = bfu(v.z >> 16);
        d[6] = bfu(v.w & 0xFFFFu); d[7] = bfu(v.w >> 16);
      }
    }
  }
  __syncthreads();
  float acc[H_];
  #pragma unroll
  for (int h = 0; h < H_; ++h) acc[h] = 0.f;
  #pragma unroll
  for (int c = 0; c < 3; ++c) {
    const float* chp = xb + (size_t)(3*tid + c)*(W_*W_);
    for (int blk = 0; blk < 8; ++blk) {
      float4 v[8];
      #pragma unroll
      for (int u = 0; u < 8; ++u) {
        const int pg = blk*8 + u;
        v[u] = *(const float4*)(chp + (pg>>2)*W_ + (pg&3)*4);
      }
      const int dbase = c*256 + blk*32;
      #pragma unroll
      for (int h = 0; h < H_; ++h) {
        const float4* qh = (const float4*)(qkl + h*D_ + dbase);
        float s0 = 0.f;
        #pragma unroll
        for (int u = 0; u < 8; ++u) {
          const float4 qq = qh[u];
          s0 += qq.x*v[u].x + qq.y*v[u].y + qq.z*v[u].z + qq.w*v[u].w;
        }
        acc[h] += s0;
      }
    }
  }
  #pragma unroll
  for (int h = 0; h < H_; ++h) sc[h][tid] = acc[h];
  __syncthreads();
  {
    const int wv = tid >> 6, lane = tid & 63;
    #pragma unroll
    for (int hh = 0; hh < 3; ++hh) {
      const int h = wv*3 + hh;
      float4 v = *(const float4*)(&sc[h][lane*4]);
      float m = fmaxf(fmaxf(v.x, v.y), fmaxf(v.z, v.w));
      #pragma unroll
      for (int off = 32; off > 0; off >>= 1) m = fmaxf(m, __shfl_xor(m, off));
      const float e0 = __expf(v.x - m), e1 = __expf(v.y - m),
                  e2 = __expf(v.z - m), e3 = __expf(v.w - m);
      float ss = (e0+e1)+(e2+e3);
      #pragma unroll
      for (int off = 32; off > 0; off >>= 1) ss += __shfl_xor(ss, off);
      const float inv = 1.0f / ss;
      *(float4*)(&sc[h][lane*4]) = make_float4(e0*inv, e1*inv, e2*inv, e3*inv);
    }
  }
  __syncthreads();
  float wacc[H_][3];
  #pragma unroll
  for (int h = 0; h < H_; ++h) { wacc[h][0]=0.f; wacc[h][1]=0.f; wacc[h][2]=0.f; }
  const float* xp0 = xb + (tid>>4)*W_ + (tid&15);
  for (int s = 0; s < S_; ++s) {
    const float p0 = xp0[(size_t)(3*s+0)*(W_*W_)];
    const float p1 = xp0[(size_t)(3*s+1)*(W_*W_)];
    const float p2 = xp0[(size_t)(3*s+2)*(W_*W_)];
    #pragma unroll
    for (int h = 0; h < H_; ++h) {
      const float at = sc[h][s];
      wacc[h][0] += at*p0; wacc[h][1] += at*p1; wacc[h][2] += at*p2;
    }
  }
  unsigned short* wp = wout + (size_t)bt*H_*D_;
  #pragma unroll
  for (int h = 0; h < H_; ++h)
    #pragma unroll
    for (int c = 0; c < 3; ++c)
      wp[h*D_ + c*256 + tid] = f2bf(wacc[h][c]);
}
// ------------------------------------------------------------------

extern "C" void kernel_launch(void* const* d_in, const int* in_sizes, int n_in,
                              void* d_out, int out_size, void* d_ws, size_t ws_size,
                              hipStream_t stream) {
  const float* x   = (const float*)d_in[0];
  const float* ipw = (const float*)d_in[1];
  const float* ipb = (const float*)d_in[2];
  const float* ow  = (const float*)d_in[3];
  const float* ob  = (const float*)d_in[4];
  float* out = (float*)d_out;

  float* q    = (float*)d_ws;                       // 1.5 MB
  float* qp   = q    + (size_t)BT_*D_;              // 1.5 MB
  unsigned short* qk = (unsigned short*)(qp + (size_t)BT_*D_);   // bf16 (region 18.9 MB)
  unsigned short* wb = (unsigned short*)(qp + (size_t)BT_*D_ + (size_t)BT_*H_*D_);  // bf16
  float* ctxb = qp + (size_t)BT_*D_ + (size_t)BT_*H_*D_*2;       // 1.5 MB
  unsigned short* packed = (unsigned short*)(ctxb + (size_t)BT_*D_);  // 201.3 MB

  const size_t need_main = ((size_t)BT_*D_*3 + (size_t)BT_*H_*D_*2) * 4
                         + (size_t)BT_*D_*S_*2;

  if (ws_size >= need_main) {
    k_pack <<<dim3(4096), dim3(384), 0, stream>>>(x, packed, q);
    k_qp   <<<dim3(768),  dim3(256), 0, stream>>>(q, ipw, ipb, qp);
    k_fold <<<dim3(2304), dim3(256), 0, stream>>>(qp, ipw, qk);
    k_attn4<<<dim3(BT_),  dim3(512), 0, stream>>>(packed, qk, wb);
    k_ctx  <<<dim3(768),  dim3(256), 0, stream>>>(wb, ipw, ipb, ctxb);
    k_out  <<<dim3(768),  dim3(256), 0, stream>>>(ctxb, ow, ob, out);
  } else {
    k_q    <<<dim3(8*D_), dim3(256), 0, stream>>>(x, q);
    k_qp   <<<dim3(768),  dim3(256), 0, stream>>>(q, ipw, ipb, qp);
    k_fold <<<dim3(2304), dim3(256), 0, stream>>>(qp, ipw, qk);
    k_attn <<<dim3(BT_),  dim3(256), 0, stream>>>(x, qk, wb);
    k_ctx  <<<dim3(768),  dim3(256), 0, stream>>>(wb, ipw, ipb, ctxb);
    k_out  <<<dim3(768),  dim3(256), 0, stream>>>(ctxb, ow, ob, out);
  }
}